// Round 2
// baseline (29109.335 us; speedup 1.0000x reference)
//
#include <hip/hip_runtime.h>
#include <math.h>

#define NB 16
#define NSY 180
#define NSX 360
#define NCIN 16
#define NW 32
#define NMODES 32
#define NPIX (NSY*NSX)     // 64800
#define NPTS (NB*NPIX)     // 1036800

// fixed-region sizes (floats)
#define SZ_H   33177600    // [16][32][180][360]
#define SZ_VY  11520       // [32][180][2]
#define SZ_VX  23040       // [32][360][2]
#define SZ_GX  384
#define SZ_GY  192
#define SZ_W1F 262144      // [4][32][32][32][2]
#define SZ_W2F 262144
#define SZ_F1T 4096
// per-batch chunk sizes (floats)
#define SZ_X2_PB 2073600   // [32][180][360]  (aliases ft: [32][32][360][2]=737280 <= this)
#define SZ_OY_PB 737280    // [32][32][360][2]
#define SZ_OX_PB 368640    // [32][32][180][2]

__device__ __forceinline__ float gelu_f(float v){
  return 0.5f*v*(1.0f + erff(v*0.70710678118654752440f));
}

// ---------------- prep: grid coords, Vandermonde, fc1 transpose ----------------
__global__ __launch_bounds__(256) void k_prep(const float* __restrict__ sx,
    const float* __restrict__ sy, const float* __restrict__ fc1_w,
    float* __restrict__ Vy, float* __restrict__ Vx,
    float* __restrict__ gx, float* __restrict__ gy, float* __restrict__ f1T){
  int idx = blockIdx.x*256 + threadIdx.x;
  float sx0 = sx[0], sxL = sx[NSX-1];
  float sy0 = sy[0], syL = sy[NSY-1];
  if (idx < NSX) gx[idx] = (sx[idx]-sx0)/sxL;
  if (idx < NSY) gy[idx] = (sy[idx]-sy0)/syL;
  if (idx < NMODES*NSY){
    int k = idx/NSY, m = idx%NSY;
    float p = (sy[m]-sy0)/(syL-sy0);
    float ang = -6.28318530717958647692f * (float)k * p;
    float s, c; sincosf(ang, &s, &c);
    const float sc = 0.07453559924999298980f;  // 1/sqrt(180)
    Vy[(k*NSY+m)*2+0] = c*sc;
    Vy[(k*NSY+m)*2+1] = s*sc;
  }
  if (idx < NMODES*NSX){
    int k = idx/NSX, n = idx%NSX;
    float p = (sx[n]-sx0)/(sxL-sx0);
    float ang = -6.28318530717958647692f * (float)k * p;
    float s, c; sincosf(ang, &s, &c);
    const float sc = 0.05270462766947298886f;  // 1/sqrt(360)
    Vx[(k*NSX+n)*2+0] = c*sc;
    Vx[(k*NSX+n)*2+1] = s*sc;
  }
  if (idx < 128*32){
    int j = idx >> 5, c = idx & 31;
    f1T[idx] = fc1_w[c*128 + j];
  }
}

// ---------------- fold pointwise w1 into the mode-mix weights ----------------
// w1f[i][in][k][o] = sum_c w1m[i][o][c] * fw[i][in][c][k]   (complex, interleaved)
__global__ __launch_bounds__(256) void k_fold(const float* __restrict__ fw1,
    const float* __restrict__ fw2, const float* __restrict__ w1m,
    float* __restrict__ w1f, float* __restrict__ w2f){
  int id = blockIdx.x*256 + threadIdx.x;      // 0..262143
  int half = id >> 17;
  int r = id & 131071;
  int i  = r >> 15;
  int in = (r >> 10) & 31;
  int k  = (r >> 5) & 31;
  int o  = r & 31;
  const float* src = half ? fw2 : fw1;
  const float* wm  = w1m + i*1024 + o*32;
  const float* sp  = src + ((size_t)((i*32+in)*1024 + k))*2;  // + c*64
  float sR = 0.f, sI = 0.f;
  #pragma unroll
  for (int c=0;c<32;c++){
    float w = wm[c];
    sR += w * sp[c*64];
    sI += w * sp[c*64+1];
  }
  float* dst = half ? w2f : w1f;
  size_t oi = ((size_t)((i*32+in)*32 + k)*32 + o)*2;
  dst[oi] = sR; dst[oi+1] = sI;
}

// ---------------- fc0: [x, gx, gy] @ fc0_w + b -> h[b][c][m][n] ----------------
__global__ __launch_bounds__(256) void k_fc0(const float* __restrict__ x,
    const float* __restrict__ gx, const float* __restrict__ gy,
    const float* __restrict__ fw, const float* __restrict__ fb,
    float* __restrict__ h){
  int p = blockIdx.x*256 + threadIdx.x;
  if (p >= NPTS) return;
  int b = p/NPIX, r = p%NPIX, m = r/NSX, n = r%NSX;
  const float* xp = x + (size_t)p*NCIN;
  float xv[NCIN+2];
  #pragma unroll
  for (int j=0;j<NCIN;j++) xv[j] = xp[j];
  xv[16] = gx[n]; xv[17] = gy[m];
  float acc[NW];
  #pragma unroll
  for (int o=0;o<NW;o++) acc[o] = fb[o];
  #pragma unroll
  for (int j=0;j<NCIN+2;j++){
    float v = xv[j];
    #pragma unroll
    for (int o=0;o<NW;o++) acc[o] += v*fw[j*32+o];
  }
  float* hp = h + (size_t)b*NW*NPIX + r;
  #pragma unroll
  for (int o=0;o<NW;o++) hp[(size_t)o*NPIX] = acc[o];
}

// ---------------- forward DFT over y: ft[bb][c][k][n][2] = sum_m h[b0+bb][c][m][n]*Vy[k][m]
__global__ __launch_bounds__(256) void k_fwd_y(const float* __restrict__ h,
    const float* __restrict__ Vy, float* __restrict__ ft, int b0){
  __shared__ __align__(16) float hl[20][64];
  __shared__ float vyl[32][42];
  int bx = blockIdx.x;
  int nt = bx % 6; int c = (bx/6) & 31; int bb = bx/192;
  int n0 = nt*64;
  int tid = threadIdx.x;
  int n_loc = (tid & 15)*4, k0 = (tid >> 4)*2;
  const float* hb = h + (size_t)((b0+bb)*NW + c)*NPIX;
  float aR[2][4] = {{0.f}}, aI[2][4] = {{0.f}};
  for (int mc=0; mc<NSY; mc+=20){
    #pragma unroll
    for (int rep=0; rep<5; rep++){
      int idx = tid + rep*256;
      int rr = idx >> 6, nn = idx & 63;
      hl[rr][nn] = (n0+nn < NSX) ? hb[(mc+rr)*NSX + n0 + nn] : 0.f;
    }
    #pragma unroll
    for (int rep=0; rep<5; rep++){
      int idx = tid + rep*256;          // < 1280
      int kk = idx/40, pp = idx%40;
      vyl[kk][pp] = Vy[kk*360 + mc*2 + pp];
    }
    __syncthreads();
    #pragma unroll 4
    for (int rr=0; rr<20; rr++){
      float4 hv = *(const float4*)&hl[rr][n_loc];
      #pragma unroll
      for (int jk=0;jk<2;jk++){
        float vR = vyl[k0+jk][rr*2], vI = vyl[k0+jk][rr*2+1];
        aR[jk][0] += hv.x*vR; aI[jk][0] += hv.x*vI;
        aR[jk][1] += hv.y*vR; aI[jk][1] += hv.y*vI;
        aR[jk][2] += hv.z*vR; aI[jk][2] += hv.z*vI;
        aR[jk][3] += hv.w*vR; aI[jk][3] += hv.w*vI;
      }
    }
    __syncthreads();
  }
  size_t base = (size_t)(bb*NW + c)*NMODES;
  #pragma unroll
  for (int jk=0;jk<2;jk++){
    #pragma unroll
    for (int jn=0;jn<4;jn++){
      int n = n0 + n_loc + jn;
      if (n < NSX){
        *(float2*)&ft[(base + k0 + jk)*(NSX*2) + n*2] = make_float2(aR[jk][jn], aI[jk][jn]);
      }
    }
  }
}

// ---------------- forward DFT over x: ft[bb][c][k][m][2] = sum_n h[b0+bb][c][m][n]*Vx[k][n]
__global__ __launch_bounds__(256) void k_fwd_x(const float* __restrict__ h,
    const float* __restrict__ Vx, float* __restrict__ ft, int b0){
  __shared__ float hl[64][41];
  __shared__ float vxl[32][82];
  int bx = blockIdx.x;
  int mt = bx % 3; int c = (bx/3) & 31; int bb = bx/96;
  int m0 = mt*64;
  int tid = threadIdx.x;
  int m_loc = (tid & 15)*4, k0 = (tid >> 4)*2;
  const float* hb = h + (size_t)((b0+bb)*NW + c)*NPIX;
  float aR[2][4] = {{0.f}}, aI[2][4] = {{0.f}};
  for (int nc=0; nc<NSX; nc+=40){
    #pragma unroll
    for (int rep=0; rep<10; rep++){
      int idx = tid + rep*256;          // < 2560
      int mm = idx/40, pp = idx%40;
      hl[mm][pp] = (m0+mm < NSY) ? hb[(m0+mm)*NSX + nc + pp] : 0.f;
    }
    #pragma unroll
    for (int rep=0; rep<10; rep++){
      int idx = tid + rep*256;
      int kk = idx/80, pp = idx%80;
      vxl[kk][pp] = Vx[kk*720 + nc*2 + pp];
    }
    __syncthreads();
    #pragma unroll 2
    for (int rr=0; rr<40; rr++){
      float h0 = hl[m_loc][rr], h1 = hl[m_loc+1][rr];
      float h2 = hl[m_loc+2][rr], h3 = hl[m_loc+3][rr];
      #pragma unroll
      for (int jk=0;jk<2;jk++){
        float vR = vxl[k0+jk][rr*2], vI = vxl[k0+jk][rr*2+1];
        aR[jk][0] += h0*vR; aI[jk][0] += h0*vI;
        aR[jk][1] += h1*vR; aI[jk][1] += h1*vI;
        aR[jk][2] += h2*vR; aI[jk][2] += h2*vI;
        aR[jk][3] += h3*vR; aI[jk][3] += h3*vI;
      }
    }
    __syncthreads();
  }
  size_t base = (size_t)(bb*NW + c)*NMODES;
  #pragma unroll
  for (int jk=0;jk<2;jk++){
    #pragma unroll
    for (int jm=0;jm<4;jm++){
      int m = m0 + m_loc + jm;
      if (m < NSY){
        *(float2*)&ft[(base + k0 + jk)*(NSY*2) + m*2] = make_float2(aR[jk][jm], aI[jk][jm]);
      }
    }
  }
}

// ---------------- per-mode complex channel mix (with folded w1):
// oo[bb][o][k][n] = sum_in ft[bb][in][k][n] * wf[in][k][o]
__global__ __launch_bounds__(192) void k_mix(const float* __restrict__ ft,
    const float* __restrict__ wf, float* __restrict__ oo, int Nlen, int ntiles){
  int bx = blockIdx.x;
  int nt = bx % ntiles; int k = (bx/ntiles) & 31; int b = bx/(ntiles*32);
  int tid = threadIdx.x;
  int n = nt*192 + tid;
  bool valid = n < Nlen;
  int nn = valid ? n : (Nlen-1);
  const float* fb = ft + ((size_t)(b*NW)*NMODES + k)*((size_t)Nlen*2) + nn*2;
  const float* wb = wf + (size_t)k*64;
  float aR[32], aI[32];
  #pragma unroll
  for (int o=0;o<32;o++){ aR[o]=0.f; aI[o]=0.f; }
  for (int in=0; in<32; in++){
    float2 f = *(const float2*)&fb[(size_t)in*NMODES*Nlen*2];
    const float* wrow = wb + in*2048;
    #pragma unroll
    for (int o=0;o<32;o++){
      float wR = wrow[o*2], wI = wrow[o*2+1];
      aR[o] += f.x*wR - f.y*wI;
      aI[o] += f.x*wI + f.y*wR;
    }
  }
  if (valid){
    #pragma unroll
    for (int o=0;o<32;o++){
      *(float2*)&oo[((size_t)(b*NW + o)*NMODES + k)*((size_t)Nlen*2) + n*2]
          = make_float2(aR[o], aI[o]);
    }
  }
}

// ---------------- fused inverse DFT (y + x) + bias b1 -> x2[bb][o][m][n] ----------------
__global__ __launch_bounds__(256) void k_inv(const float* __restrict__ oy,
    const float* __restrict__ ox, const float* __restrict__ Vy,
    const float* __restrict__ Vx, const float* __restrict__ b1,
    float* __restrict__ x2){
  __shared__ __align__(16) float oyl[32][64][2];  // 16 KB
  __shared__ __align__(16) float oxl[32][32][2];  //  8 KB
  __shared__ __align__(16) float vyl[32][32][2];  //  8 KB
  __shared__ __align__(16) float vxl[32][64][2];  // 16 KB
  int bx = blockIdx.x;
  int ntile = bx % 6; int mtile = (bx/6) % 6; int o = (bx/36) & 31; int bb = bx/1152;
  int m0 = mtile*32, n0 = ntile*64;
  int tid = threadIdx.x;
  const float* oyb = oy + (size_t)(bb*NW + o)*NMODES*(NSX*2);
  const float* oxb = ox + (size_t)(bb*NW + o)*NMODES*(NSY*2);
  #pragma unroll
  for (int rep=0; rep<16; rep++){
    int idx = tid + rep*256;  // 4096
    int k = idx >> 7, rest = idx & 127, nn = rest >> 1, ri = rest & 1;
    int n = n0 + nn;
    ((float*)oyl)[idx] = (n < NSX) ? oyb[k*(NSX*2) + n*2 + ri] : 0.f;
    ((float*)vxl)[idx] = (n < NSX) ? Vx[k*(NSX*2) + n*2 + ri] : 0.f;
  }
  #pragma unroll
  for (int rep=0; rep<8; rep++){
    int idx = tid + rep*256;  // 2048
    int k = idx >> 6, rest = idx & 63, mm = rest >> 1, ri = rest & 1;
    int m = m0 + mm;
    ((float*)oxl)[idx] = (m < NSY) ? oxb[k*(NSY*2) + m*2 + ri] : 0.f;
    ((float*)vyl)[idx] = (m < NSY) ? Vy[k*(NSY*2) + m*2 + ri] : 0.f;
  }
  __syncthreads();
  int n_loc = (tid & 15)*4, m_loc = (tid >> 4)*2;
  float acc[2][4] = {{0.f}};
  for (int k=0;k<32;k++){
    float4 a0 = *(const float4*)&oyl[k][n_loc][0];
    float4 a1 = *(const float4*)&oyl[k][n_loc+2][0];
    float4 c0 = *(const float4*)&vxl[k][n_loc][0];
    float4 c1 = *(const float4*)&vxl[k][n_loc+2][0];
    float4 bv = *(const float4*)&oxl[k][m_loc][0];
    float4 dv = *(const float4*)&vyl[k][m_loc][0];
    float oyR[4] = {a0.x, a0.z, a1.x, a1.z};
    float oyI[4] = {a0.y, a0.w, a1.y, a1.w};
    float vxR[4] = {c0.x, c0.z, c1.x, c1.z};
    float vxI[4] = {c0.y, c0.w, c1.y, c1.w};
    float oxR[2] = {bv.x, bv.z}, oxI[2] = {bv.y, bv.w};
    float vyR[2] = {dv.x, dv.z}, vyI[2] = {dv.y, dv.w};
    #pragma unroll
    for (int jm=0;jm<2;jm++){
      #pragma unroll
      for (int jn=0;jn<4;jn++){
        acc[jm][jn] += oyR[jn]*vyR[jm] + oyI[jn]*vyI[jm]
                     + oxR[jm]*vxR[jn] + oxI[jm]*vxI[jn];
      }
    }
  }
  float bias = b1[o];
  float* xb = x2 + (size_t)(bb*NW + o)*NPIX;
  #pragma unroll
  for (int jm=0;jm<2;jm++){
    int m = m0 + m_loc + jm;
    if (m < NSY){
      #pragma unroll
      for (int jn=0;jn<4;jn++){
        int n = n0 + n_loc + jn;
        if (n < NSX) xb[m*NSX + n] = acc[jm][jn] + bias;
      }
    }
  }
}

// ---------------- pointwise: h = (gelu?)(W2 @ gelu(x2) + b2) + h ----------------
__global__ __launch_bounds__(256) void k_pw(const float* __restrict__ x2,
    const float* __restrict__ w2m, const float* __restrict__ b2,
    float* __restrict__ h, int last, int b0, int nloc){
  int p = blockIdx.x*256 + threadIdx.x;
  if (p >= nloc*NPIX) return;
  int bb = p/NPIX, r = p%NPIX;
  const float* xb = x2 + (size_t)bb*NW*NPIX + r;
  float t[NW];
  #pragma unroll
  for (int c=0;c<NW;c++) t[c] = gelu_f(xb[(size_t)c*NPIX]);
  float* hb = h + (size_t)(b0+bb)*NW*NPIX + r;
  for (int o=0;o<NW;o++){
    float a = b2[o];
    #pragma unroll
    for (int c=0;c<NW;c++) a += t[c]*w2m[o*32+c];
    float g = last ? a : gelu_f(a);
    hb[(size_t)o*NPIX] += g;
  }
}

// ---------------- fc1 + gelu + fc2 ----------------
__global__ __launch_bounds__(256) void k_fc12(const float* __restrict__ h,
    const float* __restrict__ f1T, const float* __restrict__ f1b,
    const float* __restrict__ f2w, const float* __restrict__ f2b,
    float* __restrict__ out){
  int p = blockIdx.x*256 + threadIdx.x;
  if (p >= NPTS) return;
  int b = p/NPIX, r = p%NPIX;
  const float* hb = h + (size_t)b*NW*NPIX + r;
  float t[NW];
  #pragma unroll
  for (int c=0;c<NW;c++) t[c] = hb[(size_t)c*NPIX];
  float acc = f2b[0];
  for (int j=0;j<128;j++){
    float s = f1b[j];
    const float* wr = f1T + j*32;
    #pragma unroll
    for (int c=0;c<NW;c++) s += t[c]*wr[c];
    acc += gelu_f(s)*f2w[j];
  }
  out[p] = acc;
}

extern "C" void kernel_launch(void* const* d_in, const int* in_sizes, int n_in,
                              void* d_out, int out_size, void* d_ws, size_t ws_size,
                              hipStream_t stream) {
  const float* x     = (const float*)d_in[0];
  const float* sx    = (const float*)d_in[1];
  const float* sy    = (const float*)d_in[2];
  const float* fc0_w = (const float*)d_in[3];
  const float* fc0_b = (const float*)d_in[4];
  const float* fw1   = (const float*)d_in[5];
  const float* fw2   = (const float*)d_in[6];
  const float* w1m   = (const float*)d_in[7];
  const float* b1    = (const float*)d_in[8];
  const float* w2m   = (const float*)d_in[9];
  const float* b2    = (const float*)d_in[10];
  const float* fc1_w = (const float*)d_in[11];
  const float* fc1_b = (const float*)d_in[12];
  const float* fc2_w = (const float*)d_in[13];
  const float* fc2_b = (const float*)d_in[14];
  float* out = (float*)d_out;

  float* ws = (float*)d_ws;
  // fixed layout
  size_t off = 0;
  float* h   = ws + off; off += SZ_H;
  float* Vy  = ws + off; off += SZ_VY;
  float* Vx  = ws + off; off += SZ_VX;
  float* gx  = ws + off; off += SZ_GX;
  float* gy  = ws + off; off += SZ_GY;
  float* w1f = ws + off; off += SZ_W1F;
  float* w2f = ws + off; off += SZ_W2F;
  float* f1T = ws + off; off += SZ_F1T;
  const size_t fixed = off;
  const size_t per_batch = (size_t)SZ_X2_PB + SZ_OY_PB + SZ_OX_PB;  // 3,179,520 floats

  // pick largest batch-chunk NC in {16,8,4,2,1} that fits ws_size (ws_size is
  // constant across calls -> identical work every call, graph-capture safe)
  int NC = 16;
  for (; NC > 1; NC >>= 1) {
    if ((fixed + (size_t)NC*per_batch)*sizeof(float) <= ws_size) break;
  }
  float* x2ft = ws + fixed;                           // x2 aliases ft (ft dead at k_inv)
  float* oy   = x2ft + (size_t)NC*SZ_X2_PB;
  float* ox   = oy   + (size_t)NC*SZ_OY_PB;

  k_prep<<<45, 256, 0, stream>>>(sx, sy, fc1_w, Vy, Vx, gx, gy, f1T);
  k_fold<<<1024, 256, 0, stream>>>(fw1, fw2, w1m, w1f, w2f);
  k_fc0<<<4050, 256, 0, stream>>>(x, gx, gy, fc0_w, fc0_b, h);

  for (int i=0;i<4;i++){
    for (int b0=0; b0<NB; b0+=NC){
      k_fwd_y<<<NC*192, 256, 0, stream>>>(h, Vy, x2ft, b0);
      k_mix<<<NC*64, 192, 0, stream>>>(x2ft, w1f + (size_t)i*65536, oy, NSX, 2);
      k_fwd_x<<<NC*96, 256, 0, stream>>>(h, Vx, x2ft, b0);
      k_mix<<<NC*32, 192, 0, stream>>>(x2ft, w2f + (size_t)i*65536, ox, NSY, 1);
      k_inv<<<NC*1152, 256, 0, stream>>>(oy, ox, Vy, Vx, b1 + i*32, x2ft);
      k_pw<<<(NC*NPIX + 255)/256, 256, 0, stream>>>(x2ft, w2m + i*1024, b2 + i*32, h,
                                                    (int)(i==3), b0, NC);
    }
  }

  k_fc12<<<4050, 256, 0, stream>>>(h, f1T, fc1_b, fc2_w, fc2_b, out);
}

// Round 3
// 4479.122 us; speedup vs baseline: 6.4989x; 6.4989x over previous
//
#include <hip/hip_runtime.h>
#include <math.h>

#define NB 16
#define NSY 180
#define NSX 360
#define NCIN 16
#define NW 32
#define NMODES 32
#define NPIX (NSY*NSX)     // 64800
#define NPTS (NB*NPIX)     // 1036800

// fixed-region sizes (floats)
#define SZ_H   33177600    // [16][32][180][360]
#define SZ_VY  11520       // [32][180][2]
#define SZ_VX  23040       // [32][360][2]
#define SZ_GX  384
#define SZ_GY  192
#define SZ_W1F 262144      // [4][32][32][32][2]
#define SZ_W2F 262144
#define SZ_F1T 4096
// per-batch chunk sizes (floats)
#define SZ_FT_PB 737280    // [32][32][360][2]
#define SZ_OY_PB 737280    // [32][32][360][2]
#define SZ_OX_PB 368640    // [32][32][180][2]

__device__ __forceinline__ float gelu_f(float v){
  return 0.5f*v*(1.0f + erff(v*0.70710678118654752440f));
}

// ---------------- prep: grid coords, Vandermonde, fc1 transpose ----------------
__global__ __launch_bounds__(256) void k_prep(const float* __restrict__ sx,
    const float* __restrict__ sy, const float* __restrict__ fc1_w,
    float* __restrict__ Vy, float* __restrict__ Vx,
    float* __restrict__ gx, float* __restrict__ gy, float* __restrict__ f1T){
  int idx = blockIdx.x*256 + threadIdx.x;
  float sx0 = sx[0], sxL = sx[NSX-1];
  float sy0 = sy[0], syL = sy[NSY-1];
  if (idx < NSX) gx[idx] = (sx[idx]-sx0)/sxL;
  if (idx < NSY) gy[idx] = (sy[idx]-sy0)/syL;
  if (idx < NMODES*NSY){
    int k = idx/NSY, m = idx%NSY;
    float p = (sy[m]-sy0)/(syL-sy0);
    float ang = -6.28318530717958647692f * (float)k * p;
    float s, c; sincosf(ang, &s, &c);
    const float sc = 0.07453559924999298980f;  // 1/sqrt(180)
    Vy[(k*NSY+m)*2+0] = c*sc;
    Vy[(k*NSY+m)*2+1] = s*sc;
  }
  if (idx < NMODES*NSX){
    int k = idx/NSX, n = idx%NSX;
    float p = (sx[n]-sx0)/(sxL-sx0);
    float ang = -6.28318530717958647692f * (float)k * p;
    float s, c; sincosf(ang, &s, &c);
    const float sc = 0.05270462766947298886f;  // 1/sqrt(360)
    Vx[(k*NSX+n)*2+0] = c*sc;
    Vx[(k*NSX+n)*2+1] = s*sc;
  }
  if (idx < 128*32){
    int j = idx >> 5, c = idx & 31;
    f1T[idx] = fc1_w[c*128 + j];
  }
}

// ---------------- fold pointwise w1 into the mode-mix weights ----------------
// w1f[i][in][k][o] = sum_c w1m[i][o][c] * fw[i][in][c][k]   (complex, interleaved)
__global__ __launch_bounds__(256) void k_fold(const float* __restrict__ fw1,
    const float* __restrict__ fw2, const float* __restrict__ w1m,
    float* __restrict__ w1f, float* __restrict__ w2f){
  int id = blockIdx.x*256 + threadIdx.x;      // 0..262143
  int half = id >> 17;
  int r = id & 131071;
  int i  = r >> 15;
  int in = (r >> 10) & 31;
  int k  = (r >> 5) & 31;
  int o  = r & 31;
  const float* src = half ? fw2 : fw1;
  const float* wm  = w1m + i*1024 + o*32;
  const float* sp  = src + ((size_t)((i*32+in)*1024 + k))*2;  // + c*64
  float sR = 0.f, sI = 0.f;
  #pragma unroll
  for (int c=0;c<32;c++){
    float w = wm[c];
    sR += w * sp[c*64];
    sI += w * sp[c*64+1];
  }
  float* dst = half ? w2f : w1f;
  size_t oi = ((size_t)((i*32+in)*32 + k)*32 + o)*2;
  dst[oi] = sR; dst[oi+1] = sI;
}

// ---------------- fc0: [x, gx, gy] @ fc0_w + b -> h[b][c][m][n] ----------------
__global__ __launch_bounds__(256) void k_fc0(const float* __restrict__ x,
    const float* __restrict__ gx, const float* __restrict__ gy,
    const float* __restrict__ fw, const float* __restrict__ fb,
    float* __restrict__ h){
  int p = blockIdx.x*256 + threadIdx.x;
  if (p >= NPTS) return;
  int b = p/NPIX, r = p%NPIX, m = r/NSX, n = r%NSX;
  const float* xp = x + (size_t)p*NCIN;
  float xv[NCIN+2];
  #pragma unroll
  for (int j=0;j<NCIN;j++) xv[j] = xp[j];
  xv[16] = gx[n]; xv[17] = gy[m];
  float acc[NW];
  #pragma unroll
  for (int o=0;o<NW;o++) acc[o] = fb[o];
  #pragma unroll
  for (int j=0;j<NCIN+2;j++){
    float v = xv[j];
    #pragma unroll
    for (int o=0;o<NW;o++) acc[o] += v*fw[j*32+o];
  }
  float* hp = h + (size_t)b*NW*NPIX + r;
  #pragma unroll
  for (int o=0;o<NW;o++) hp[(size_t)o*NPIX] = acc[o];
}

// ---------------- forward DFT over y: ft[bb][c][k][n][2] = sum_m h[b0+bb][c][m][n]*Vy[k][m]
__global__ __launch_bounds__(256) void k_fwd_y(const float* __restrict__ h,
    const float* __restrict__ Vy, float* __restrict__ ft, int b0){
  __shared__ __align__(16) float hl[20][64];
  __shared__ float vyl[32][42];
  int bx = blockIdx.x;
  int nt = bx % 6; int c = (bx/6) & 31; int bb = bx/192;
  int n0 = nt*64;
  int tid = threadIdx.x;
  int n_loc = (tid & 15)*4, k0 = (tid >> 4)*2;
  const float* hb = h + (size_t)((b0+bb)*NW + c)*NPIX;
  float aR[2][4] = {{0.f}}, aI[2][4] = {{0.f}};
  for (int mc=0; mc<NSY; mc+=20){
    #pragma unroll
    for (int rep=0; rep<5; rep++){
      int idx = tid + rep*256;
      int rr = idx >> 6, nn = idx & 63;
      hl[rr][nn] = (n0+nn < NSX) ? hb[(mc+rr)*NSX + n0 + nn] : 0.f;
    }
    #pragma unroll
    for (int rep=0; rep<5; rep++){
      int idx = tid + rep*256;          // < 1280
      int kk = idx/40, pp = idx%40;
      vyl[kk][pp] = Vy[kk*360 + mc*2 + pp];
    }
    __syncthreads();
    #pragma unroll 4
    for (int rr=0; rr<20; rr++){
      float4 hv = *(const float4*)&hl[rr][n_loc];
      #pragma unroll
      for (int jk=0;jk<2;jk++){
        float vR = vyl[k0+jk][rr*2], vI = vyl[k0+jk][rr*2+1];
        aR[jk][0] += hv.x*vR; aI[jk][0] += hv.x*vI;
        aR[jk][1] += hv.y*vR; aI[jk][1] += hv.y*vI;
        aR[jk][2] += hv.z*vR; aI[jk][2] += hv.z*vI;
        aR[jk][3] += hv.w*vR; aI[jk][3] += hv.w*vI;
      }
    }
    __syncthreads();
  }
  size_t base = (size_t)(bb*NW + c)*NMODES;
  #pragma unroll
  for (int jk=0;jk<2;jk++){
    #pragma unroll
    for (int jn=0;jn<4;jn++){
      int n = n0 + n_loc + jn;
      if (n < NSX){
        *(float2*)&ft[(base + k0 + jk)*(NSX*2) + n*2] = make_float2(aR[jk][jn], aI[jk][jn]);
      }
    }
  }
}

// ---------------- forward DFT over x: ft[bb][c][k][m][2] = sum_n h[b0+bb][c][m][n]*Vx[k][n]
__global__ __launch_bounds__(256) void k_fwd_x(const float* __restrict__ h,
    const float* __restrict__ Vx, float* __restrict__ ft, int b0){
  __shared__ float hl[64][41];
  __shared__ float vxl[32][82];
  int bx = blockIdx.x;
  int mt = bx % 3; int c = (bx/3) & 31; int bb = bx/96;
  int m0 = mt*64;
  int tid = threadIdx.x;
  int m_loc = (tid & 15)*4, k0 = (tid >> 4)*2;
  const float* hb = h + (size_t)((b0+bb)*NW + c)*NPIX;
  float aR[2][4] = {{0.f}}, aI[2][4] = {{0.f}};
  for (int nc=0; nc<NSX; nc+=40){
    #pragma unroll
    for (int rep=0; rep<10; rep++){
      int idx = tid + rep*256;          // < 2560
      int mm = idx/40, pp = idx%40;
      hl[mm][pp] = (m0+mm < NSY) ? hb[(m0+mm)*NSX + nc + pp] : 0.f;
    }
    #pragma unroll
    for (int rep=0; rep<10; rep++){
      int idx = tid + rep*256;
      int kk = idx/80, pp = idx%80;
      vxl[kk][pp] = Vx[kk*720 + nc*2 + pp];
    }
    __syncthreads();
    #pragma unroll 2
    for (int rr=0; rr<40; rr++){
      float h0 = hl[m_loc][rr], h1 = hl[m_loc+1][rr];
      float h2 = hl[m_loc+2][rr], h3 = hl[m_loc+3][rr];
      #pragma unroll
      for (int jk=0;jk<2;jk++){
        float vR = vxl[k0+jk][rr*2], vI = vxl[k0+jk][rr*2+1];
        aR[jk][0] += h0*vR; aI[jk][0] += h0*vI;
        aR[jk][1] += h1*vR; aI[jk][1] += h1*vI;
        aR[jk][2] += h2*vR; aI[jk][2] += h2*vI;
        aR[jk][3] += h3*vR; aI[jk][3] += h3*vI;
      }
    }
    __syncthreads();
  }
  size_t base = (size_t)(bb*NW + c)*NMODES;
  #pragma unroll
  for (int jk=0;jk<2;jk++){
    #pragma unroll
    for (int jm=0;jm<4;jm++){
      int m = m0 + m_loc + jm;
      if (m < NSY){
        *(float2*)&ft[(base + k0 + jk)*(NSY*2) + m*2] = make_float2(aR[jk][jm], aI[jk][jm]);
      }
    }
  }
}

// ---------------- per-mode complex channel mix (with folded w1):
// oo[bb][o][k][n] = sum_in ft[bb][in][k][n] * wf[in][k][o]
__global__ __launch_bounds__(192) void k_mix(const float* __restrict__ ft,
    const float* __restrict__ wf, float* __restrict__ oo, int Nlen, int ntiles){
  int bx = blockIdx.x;
  int nt = bx % ntiles; int k = (bx/ntiles) & 31; int b = bx/(ntiles*32);
  int tid = threadIdx.x;
  int n = nt*192 + tid;
  bool valid = n < Nlen;
  int nn = valid ? n : (Nlen-1);
  const float* fb = ft + ((size_t)(b*NW)*NMODES + k)*((size_t)Nlen*2) + nn*2;
  const float* wb = wf + (size_t)k*64;
  float aR[32], aI[32];
  #pragma unroll
  for (int o=0;o<32;o++){ aR[o]=0.f; aI[o]=0.f; }
  for (int in=0; in<32; in++){
    float2 f = *(const float2*)&fb[(size_t)in*NMODES*Nlen*2];
    const float* wrow = wb + in*2048;
    #pragma unroll
    for (int o=0;o<32;o++){
      float wR = wrow[o*2], wI = wrow[o*2+1];
      aR[o] += f.x*wR - f.y*wI;
      aI[o] += f.x*wI + f.y*wR;
    }
  }
  if (valid){
    #pragma unroll
    for (int o=0;o<32;o++){
      *(float2*)&oo[((size_t)(b*NW + o)*NMODES + k)*((size_t)Nlen*2) + n*2]
          = make_float2(aR[o], aI[o]);
    }
  }
}

// ---------------- fused inverse DFT (y+x) + b1 + gelu + W2 + b2 + (gelu) + h-residual ----
// Block: pixel tile 8m x 32n, ALL 32 channels. Phase 1: thread (o, ng) computes
// x2[o][8m][4n] in regs (K=32 modes in 4-mode LDS chunks). Phase 2: LDS handoff,
// thread-per-pixel does gelu -> W2 mix -> h +=. x2 never hits global memory.
__global__ __launch_bounds__(256) void k_invpw(const float* __restrict__ oy,
    const float* __restrict__ ox, const float* __restrict__ Vy,
    const float* __restrict__ Vx, const float* __restrict__ b1,
    const float* __restrict__ w2m, const float* __restrict__ b2,
    float* __restrict__ h, int last, int b0){
  __shared__ float oyl[32*258];   // [o][k(4)][n(32)][ri], stride_o 258 (2-way max conflicts); aliased as x2l[o][px]
  __shared__ float oxl[32*66];    // [o][k(4)][m(8)][ri], stride_o 66
  __shared__ float vyl[4*16];     // [k][m(8)][ri]
  __shared__ float vxl[4*66];     // [k][n(32)][ri], stride_k 66
  int bx = blockIdx.x;
  int mt = bx % 23; int nt = (bx/23) % 12; int bb = bx/276;
  int m0 = mt*8, n0 = nt*32;
  int tid = threadIdx.x;
  int o = tid >> 3, ng = tid & 7;
  float acc[8][4];
  #pragma unroll
  for (int m=0;m<8;m++){
    #pragma unroll
    for (int j=0;j<4;j++) acc[m][j]=0.f;
  }
  const float* oyb = oy + (size_t)(bb*32)*32*720;
  const float* oxb = ox + (size_t)(bb*32)*32*360;

  for (int kc=0; kc<32; kc+=4){
    __syncthreads();
    // stage oy tile: 128 rows (o2,k) x 64 floats; thread: row tid>>1, half tid&1
    {
      int row = tid >> 1, hf = tid & 1;
      int o2 = row >> 2, kk = row & 3;
      const float* src = oyb + ((size_t)o2*32 + (kc+kk))*720 + (size_t)n0*2 + hf*32;
      float* dst = &oyl[o2*258 + kk*64 + hf*32];
      int nbase = n0 + hf*16;
      #pragma unroll
      for (int q=0;q<8;q++){                 // 8 float4 = 32 floats (2 n each)
        int nv = nbase + 2*q;
        float4 v;
        if (nv+1 < NSX) v = *(const float4*)(src + q*4);
        else {
          v.x = (nv<NSX)? src[q*4+0] : 0.f;
          v.y = (nv<NSX)? src[q*4+1] : 0.f;
          v.z = 0.f; v.w = 0.f;
        }
        *(float2*)(dst + q*4)     = make_float2(v.x, v.y);
        *(float2*)(dst + q*4 + 2) = make_float2(v.z, v.w);
      }
    }
    // stage ox tile: 128 rows (o2,k) x 16 floats (8m x ri); threads 0..127
    if (tid < 128){
      int o2 = tid >> 2, kk = tid & 3;
      const float* src = oxb + ((size_t)o2*32 + (kc+kk))*360 + (size_t)m0*2;
      float* dst = &oxl[o2*66 + kk*16];
      #pragma unroll
      for (int q=0;q<4;q++){
        int mv = m0 + 2*q;
        float4 v;
        if (mv+1 < NSY) v = *(const float4*)(src + q*4);
        else {
          v.x = (mv<NSY)? src[q*4+0] : 0.f;
          v.y = (mv<NSY)? src[q*4+1] : 0.f;
          v.z = 0.f; v.w = 0.f;
        }
        *(float2*)(dst + q*4)     = make_float2(v.x, v.y);
        *(float2*)(dst + q*4 + 2) = make_float2(v.z, v.w);
      }
    }
    // stage vy: 4k x 8m x 2
    if (tid < 64){
      int kk = tid >> 4, f = tid & 15;
      int m = m0 + (f >> 1);
      vyl[kk*16 + f] = (m < NSY) ? Vy[(kc+kk)*360 + m*2 + (f&1)] : 0.f;
    }
    // stage vx: 4k x 32n x 2
    {
      int kk = tid >> 6, f = tid & 63;
      int n = n0 + (f >> 1);
      vxl[kk*66 + f] = (n < NSX) ? Vx[(kc+kk)*720 + n*2 + (f&1)] : 0.f;
    }
    __syncthreads();

    #pragma unroll
    for (int k=0;k<4;k++){
      float vyR[8], vyI[8], oxR[8], oxI[8];
      #pragma unroll
      for (int m=0;m<8;m++){
        float2 vy2 = *(const float2*)&vyl[k*16 + m*2];
        vyR[m]=vy2.x; vyI[m]=vy2.y;
        float2 ox2 = *(const float2*)&oxl[o*66 + k*16 + m*2];
        oxR[m]=ox2.x; oxI[m]=ox2.y;
      }
      #pragma unroll
      for (int j=0;j<4;j++){
        float2 oy2 = *(const float2*)&oyl[o*258 + k*64 + (ng*4+j)*2];
        float2 vx2 = *(const float2*)&vxl[k*66 + (ng*4+j)*2];
        #pragma unroll
        for (int m=0;m<8;m++){
          acc[m][j] += oy2.x*vyR[m] + oy2.y*vyI[m] + oxR[m]*vx2.x + oxI[m]*vx2.y;
        }
      }
    }
  }

  // handoff: x2l[o][px] (aliases oyl), px = m*32 + n_local, bias b1 added here
  __syncthreads();
  float b1v = b1[o];
  #pragma unroll
  for (int m=0;m<8;m++){
    #pragma unroll
    for (int j=0;j<2;j++){
      *(float2*)&oyl[o*258 + m*32 + ng*4 + j*2]
          = make_float2(acc[m][2*j]+b1v, acc[m][2*j+1]+b1v);
    }
  }
  __syncthreads();

  // phase 2: one pixel per thread
  int px = tid, pm = px >> 5, pn = px & 31;
  float t[32];
  #pragma unroll
  for (int c=0;c<32;c++) t[c] = gelu_f(oyl[c*258 + px]);
  int mg = m0 + pm, ngb = n0 + pn;
  if (mg < NSY && ngb < NSX){
    float* hp = h + ((size_t)(b0+bb)*NW)*NPIX + (size_t)mg*NSX + ngb;
    for (int o2=0;o2<32;o2++){
      float a = b2[o2];
      const float* wr = w2m + o2*32;
      #pragma unroll
      for (int c=0;c<32;c++) a += t[c]*wr[c];
      float g = last ? a : gelu_f(a);
      hp[(size_t)o2*NPIX] += g;
    }
  }
}

// ---------------- fc1 + gelu + fc2 ----------------
__global__ __launch_bounds__(256) void k_fc12(const float* __restrict__ h,
    const float* __restrict__ f1T, const float* __restrict__ f1b,
    const float* __restrict__ f2w, const float* __restrict__ f2b,
    float* __restrict__ out){
  int p = blockIdx.x*256 + threadIdx.x;
  if (p >= NPTS) return;
  int b = p/NPIX, r = p%NPIX;
  const float* hb = h + (size_t)b*NW*NPIX + r;
  float t[NW];
  #pragma unroll
  for (int c=0;c<NW;c++) t[c] = hb[(size_t)c*NPIX];
  float acc = f2b[0];
  for (int j=0;j<128;j++){
    float s = f1b[j];
    const float* wr = f1T + j*32;
    #pragma unroll
    for (int c=0;c<NW;c++) s += t[c]*wr[c];
    acc += gelu_f(s)*f2w[j];
  }
  out[p] = acc;
}

extern "C" void kernel_launch(void* const* d_in, const int* in_sizes, int n_in,
                              void* d_out, int out_size, void* d_ws, size_t ws_size,
                              hipStream_t stream) {
  const float* x     = (const float*)d_in[0];
  const float* sx    = (const float*)d_in[1];
  const float* sy    = (const float*)d_in[2];
  const float* fc0_w = (const float*)d_in[3];
  const float* fc0_b = (const float*)d_in[4];
  const float* fw1   = (const float*)d_in[5];
  const float* fw2   = (const float*)d_in[6];
  const float* w1m   = (const float*)d_in[7];
  const float* b1    = (const float*)d_in[8];
  const float* w2m   = (const float*)d_in[9];
  const float* b2    = (const float*)d_in[10];
  const float* fc1_w = (const float*)d_in[11];
  const float* fc1_b = (const float*)d_in[12];
  const float* fc2_w = (const float*)d_in[13];
  const float* fc2_b = (const float*)d_in[14];
  float* out = (float*)d_out;

  float* ws = (float*)d_ws;
  size_t off = 0;
  float* h   = ws + off; off += SZ_H;
  float* Vy  = ws + off; off += SZ_VY;
  float* Vx  = ws + off; off += SZ_VX;
  float* gx  = ws + off; off += SZ_GX;
  float* gy  = ws + off; off += SZ_GY;
  float* w1f = ws + off; off += SZ_W1F;
  float* w2f = ws + off; off += SZ_W2F;
  float* f1T = ws + off; off += SZ_F1T;
  const size_t fixed = off;
  const size_t per_batch = (size_t)SZ_FT_PB + SZ_OY_PB + SZ_OX_PB;  // 1,843,200 floats

  // largest batch-chunk NC that fits ws (ws_size constant across calls -> graph-safe)
  int NC = 16;
  for (; NC > 1; NC >>= 1) {
    if ((fixed + (size_t)NC*per_batch)*sizeof(float) <= ws_size) break;
  }
  float* ft = ws + fixed;
  float* oy = ft + (size_t)NC*SZ_FT_PB;
  float* ox = oy + (size_t)NC*SZ_OY_PB;

  k_prep<<<45, 256, 0, stream>>>(sx, sy, fc1_w, Vy, Vx, gx, gy, f1T);
  k_fold<<<1024, 256, 0, stream>>>(fw1, fw2, w1m, w1f, w2f);
  k_fc0<<<4050, 256, 0, stream>>>(x, gx, gy, fc0_w, fc0_b, h);

  for (int i=0;i<4;i++){
    for (int b0=0; b0<NB; b0+=NC){
      k_fwd_y<<<NC*192, 256, 0, stream>>>(h, Vy, ft, b0);
      k_mix<<<NC*64, 192, 0, stream>>>(ft, w1f + (size_t)i*65536, oy, NSX, 2);
      k_fwd_x<<<NC*96, 256, 0, stream>>>(h, Vx, ft, b0);
      k_mix<<<NC*32, 192, 0, stream>>>(ft, w2f + (size_t)i*65536, ox, NSY, 1);
      k_invpw<<<NC*276, 256, 0, stream>>>(oy, ox, Vy, Vx, b1 + i*32,
                                          w2m + (size_t)i*1024, b2 + i*32, h,
                                          (int)(i==3), b0);
    }
  }

  k_fc12<<<4050, 256, 0, stream>>>(h, f1T, fc1_b, fc2_w, fc2_b, out);
}

// Round 4
// 3424.237 us; speedup vs baseline: 8.5010x; 1.3081x over previous
//
#include <hip/hip_runtime.h>
#include <math.h>

#define NB 16
#define NSY 180
#define NSX 360
#define NCIN 16
#define NW 32
#define NMODES 32
#define NPIX (NSY*NSX)     // 64800
#define NPTS (NB*NPIX)     // 1036800

// fixed-region sizes (floats)
#define SZ_H   33177600    // [16][32][180][360]
#define SZ_VY  11520       // [32][180][2]
#define SZ_VX  23040       // [32][360][2]
#define SZ_VYT 11520       // [180][32][2]  (transposed for uniform s_load rows)
#define SZ_GX  384
#define SZ_GY  192
#define SZ_W1F 262144      // [4][32][32][32][2]
#define SZ_W2F 262144
#define SZ_F1T 4096
// per-batch chunk sizes (floats)
#define SZ_X2FT_PB 2073600 // x2 [32][180][360]; aliases ft [32][32][360][2]=737280 (ft dead at k_inv2)
#define SZ_OY_PB 737280    // [32][32][360][2]   (k-major: [o][k][n][ri])
#define SZ_OX_PB 368640    // [32][180][32][2]   (m-major: [o][m][k][ri])

__device__ __forceinline__ float gelu_f(float v){
  return 0.5f*v*(1.0f + erff(v*0.70710678118654752440f));
}

// ---------------- prep: grid coords, Vandermonde (+transpose), fc1 transpose ----------------
__global__ __launch_bounds__(256) void k_prep(const float* __restrict__ sx,
    const float* __restrict__ sy, const float* __restrict__ fc1_w,
    float* __restrict__ Vy, float* __restrict__ Vx, float* __restrict__ VyT,
    float* __restrict__ gx, float* __restrict__ gy, float* __restrict__ f1T){
  int idx = blockIdx.x*256 + threadIdx.x;
  float sx0 = sx[0], sxL = sx[NSX-1];
  float sy0 = sy[0], syL = sy[NSY-1];
  if (idx < NSX) gx[idx] = (sx[idx]-sx0)/sxL;
  if (idx < NSY) gy[idx] = (sy[idx]-sy0)/syL;
  if (idx < NMODES*NSY){
    int k = idx/NSY, m = idx%NSY;
    float p = (sy[m]-sy0)/(syL-sy0);
    float ang = -6.28318530717958647692f * (float)k * p;
    float s, c; sincosf(ang, &s, &c);
    const float sc = 0.07453559924999298980f;  // 1/sqrt(180)
    Vy[(k*NSY+m)*2+0] = c*sc;
    Vy[(k*NSY+m)*2+1] = s*sc;
    VyT[(m*NMODES+k)*2+0] = c*sc;
    VyT[(m*NMODES+k)*2+1] = s*sc;
  }
  if (idx < NMODES*NSX){
    int k = idx/NSX, n = idx%NSX;
    float p = (sx[n]-sx0)/(sxL-sx0);
    float ang = -6.28318530717958647692f * (float)k * p;
    float s, c; sincosf(ang, &s, &c);
    const float sc = 0.05270462766947298886f;  // 1/sqrt(360)
    Vx[(k*NSX+n)*2+0] = c*sc;
    Vx[(k*NSX+n)*2+1] = s*sc;
  }
  if (idx < 128*32){
    int j = idx >> 5, c = idx & 31;
    f1T[idx] = fc1_w[c*128 + j];
  }
}

// ---------------- fold pointwise w1 into the mode-mix weights ----------------
// w1f[i][in][k][o] = sum_c w1m[i][o][c] * fw[i][in][c][k]   (complex, interleaved)
__global__ __launch_bounds__(256) void k_fold(const float* __restrict__ fw1,
    const float* __restrict__ fw2, const float* __restrict__ w1m,
    float* __restrict__ w1f, float* __restrict__ w2f){
  int id = blockIdx.x*256 + threadIdx.x;      // 0..262143
  int half = id >> 17;
  int r = id & 131071;
  int i  = r >> 15;
  int in = (r >> 10) & 31;
  int k  = (r >> 5) & 31;
  int o  = r & 31;
  const float* src = half ? fw2 : fw1;
  const float* wm  = w1m + i*1024 + o*32;
  const float* sp  = src + ((size_t)((i*32+in)*1024 + k))*2;  // + c*64
  float sR = 0.f, sI = 0.f;
  #pragma unroll
  for (int c=0;c<32;c++){
    float w = wm[c];
    sR += w * sp[c*64];
    sI += w * sp[c*64+1];
  }
  float* dst = half ? w2f : w1f;
  size_t oi = ((size_t)((i*32+in)*32 + k)*32 + o)*2;
  dst[oi] = sR; dst[oi+1] = sI;
}

// ---------------- fc0: [x, gx, gy] @ fc0_w + b -> h[b][c][m][n] ----------------
__global__ __launch_bounds__(256) void k_fc0(const float* __restrict__ x,
    const float* __restrict__ gx, const float* __restrict__ gy,
    const float* __restrict__ fw, const float* __restrict__ fb,
    float* __restrict__ h){
  int p = blockIdx.x*256 + threadIdx.x;
  if (p >= NPTS) return;
  int b = p/NPIX, r = p%NPIX, m = r/NSX, n = r%NSX;
  const float* xp = x + (size_t)p*NCIN;
  float xv[NCIN+2];
  #pragma unroll
  for (int j=0;j<NCIN;j++) xv[j] = xp[j];
  xv[16] = gx[n]; xv[17] = gy[m];
  float acc[NW];
  #pragma unroll
  for (int o=0;o<NW;o++) acc[o] = fb[o];
  #pragma unroll
  for (int j=0;j<NCIN+2;j++){
    float v = xv[j];
    #pragma unroll
    for (int o=0;o<NW;o++) acc[o] += v*fw[j*32+o];
  }
  float* hp = h + (size_t)b*NW*NPIX + r;
  #pragma unroll
  for (int o=0;o<NW;o++) hp[(size_t)o*NPIX] = acc[o];
}

// ---------------- forward DFT over y: ft[bb][c][k][n][2] = sum_m h[b0+bb][c][m][n]*Vy[k][m]
__global__ __launch_bounds__(256) void k_fwd_y(const float* __restrict__ h,
    const float* __restrict__ Vy, float* __restrict__ ft, int b0){
  __shared__ __align__(16) float hl[20][64];
  __shared__ float vyl[32][42];
  int bx = blockIdx.x;
  int nt = bx % 6; int c = (bx/6) & 31; int bb = bx/192;
  int n0 = nt*64;
  int tid = threadIdx.x;
  int n_loc = (tid & 15)*4, k0 = (tid >> 4)*2;
  const float* hb = h + (size_t)((b0+bb)*NW + c)*NPIX;
  float aR[2][4] = {{0.f}}, aI[2][4] = {{0.f}};
  for (int mc=0; mc<NSY; mc+=20){
    #pragma unroll
    for (int rep=0; rep<5; rep++){
      int idx = tid + rep*256;
      int rr = idx >> 6, nn = idx & 63;
      hl[rr][nn] = (n0+nn < NSX) ? hb[(mc+rr)*NSX + n0 + nn] : 0.f;
    }
    #pragma unroll
    for (int rep=0; rep<5; rep++){
      int idx = tid + rep*256;          // < 1280
      int kk = idx/40, pp = idx%40;
      vyl[kk][pp] = Vy[kk*360 + mc*2 + pp];
    }
    __syncthreads();
    #pragma unroll 4
    for (int rr=0; rr<20; rr++){
      float4 hv = *(const float4*)&hl[rr][n_loc];
      #pragma unroll
      for (int jk=0;jk<2;jk++){
        float vR = vyl[k0+jk][rr*2], vI = vyl[k0+jk][rr*2+1];
        aR[jk][0] += hv.x*vR; aI[jk][0] += hv.x*vI;
        aR[jk][1] += hv.y*vR; aI[jk][1] += hv.y*vI;
        aR[jk][2] += hv.z*vR; aI[jk][2] += hv.z*vI;
        aR[jk][3] += hv.w*vR; aI[jk][3] += hv.w*vI;
      }
    }
    __syncthreads();
  }
  size_t base = (size_t)(bb*NW + c)*NMODES;
  #pragma unroll
  for (int jk=0;jk<2;jk++){
    #pragma unroll
    for (int jn=0;jn<4;jn++){
      int n = n0 + n_loc + jn;
      if (n < NSX){
        *(float2*)&ft[(base + k0 + jk)*(NSX*2) + n*2] = make_float2(aR[jk][jn], aI[jk][jn]);
      }
    }
  }
}

// ---------------- forward DFT over x: ft[bb][c][k][m][2] = sum_n h[b0+bb][c][m][n]*Vx[k][n]
__global__ __launch_bounds__(256) void k_fwd_x(const float* __restrict__ h,
    const float* __restrict__ Vx, float* __restrict__ ft, int b0){
  __shared__ float hl[64][41];
  __shared__ float vxl[32][82];
  int bx = blockIdx.x;
  int mt = bx % 3; int c = (bx/3) & 31; int bb = bx/96;
  int m0 = mt*64;
  int tid = threadIdx.x;
  int m_loc = (tid & 15)*4, k0 = (tid >> 4)*2;
  const float* hb = h + (size_t)((b0+bb)*NW + c)*NPIX;
  float aR[2][4] = {{0.f}}, aI[2][4] = {{0.f}};
  for (int nc=0; nc<NSX; nc+=40){
    #pragma unroll
    for (int rep=0; rep<10; rep++){
      int idx = tid + rep*256;          // < 2560
      int mm = idx/40, pp = idx%40;
      hl[mm][pp] = (m0+mm < NSY) ? hb[(m0+mm)*NSX + nc + pp] : 0.f;
    }
    #pragma unroll
    for (int rep=0; rep<10; rep++){
      int idx = tid + rep*256;
      int kk = idx/80, pp = idx%80;
      vxl[kk][pp] = Vx[kk*720 + nc*2 + pp];
    }
    __syncthreads();
    #pragma unroll 2
    for (int rr=0; rr<40; rr++){
      float h0 = hl[m_loc][rr], h1 = hl[m_loc+1][rr];
      float h2 = hl[m_loc+2][rr], h3 = hl[m_loc+3][rr];
      #pragma unroll
      for (int jk=0;jk<2;jk++){
        float vR = vxl[k0+jk][rr*2], vI = vxl[k0+jk][rr*2+1];
        aR[jk][0] += h0*vR; aI[jk][0] += h0*vI;
        aR[jk][1] += h1*vR; aI[jk][1] += h1*vI;
        aR[jk][2] += h2*vR; aI[jk][2] += h2*vI;
        aR[jk][3] += h3*vR; aI[jk][3] += h3*vI;
      }
    }
    __syncthreads();
  }
  size_t base = (size_t)(bb*NW + c)*NMODES;
  #pragma unroll
  for (int jk=0;jk<2;jk++){
    #pragma unroll
    for (int jm=0;jm<4;jm++){
      int m = m0 + m_loc + jm;
      if (m < NSY){
        *(float2*)&ft[(base + k0 + jk)*(NSY*2) + m*2] = make_float2(aR[jk][jm], aI[jk][jm]);
      }
    }
  }
}

// ---------------- per-mode complex channel mix (with folded w1):
// tpose=0: oo[bb][o][k][n][ri]   (k-major, for k_inv2 lane-resident reads)
// tpose=1: oo[bb][o][n][k][ri]   (m-major, for k_inv2 uniform s_load rows)
__global__ __launch_bounds__(192) void k_mix(const float* __restrict__ ft,
    const float* __restrict__ wf, float* __restrict__ oo, int Nlen, int ntiles,
    int tpose){
  int bx = blockIdx.x;
  int nt = bx % ntiles; int k = (bx/ntiles) & 31; int b = bx/(ntiles*32);
  int tid = threadIdx.x;
  int n = nt*192 + tid;
  bool valid = n < Nlen;
  int nn = valid ? n : (Nlen-1);
  const float* fb = ft + ((size_t)(b*NW)*NMODES + k)*((size_t)Nlen*2) + nn*2;
  const float* wb = wf + (size_t)k*64;
  float aR[32], aI[32];
  #pragma unroll
  for (int o=0;o<32;o++){ aR[o]=0.f; aI[o]=0.f; }
  for (int in=0; in<32; in++){
    float2 f = *(const float2*)&fb[(size_t)in*NMODES*Nlen*2];
    const float* wrow = wb + in*2048;
    #pragma unroll
    for (int o=0;o<32;o++){
      float wR = wrow[o*2], wI = wrow[o*2+1];
      aR[o] += f.x*wR - f.y*wI;
      aI[o] += f.x*wI + f.y*wR;
    }
  }
  if (valid){
    if (tpose){
      #pragma unroll
      for (int o=0;o<32;o++){
        *(float2*)&oo[((size_t)(b*NW + o)*Nlen + n)*64 + k*2]
            = make_float2(aR[o], aI[o]);
      }
    } else {
      #pragma unroll
      for (int o=0;o<32;o++){
        *(float2*)&oo[((size_t)(b*NW + o)*NMODES + k)*((size_t)Nlen*2) + n*2]
            = make_float2(aR[o], aI[o]);
      }
    }
  }
}

// ---------------- inverse DFT (y+x) + b1 -> x2[bb][o][m][n] ----------------
// One wave per (bb, o, n-strip, m-quarter). Lane-resident: oy[k][n], Vx[k][n]
// (128 VGPRs, loaded once, coalesced). Wave-uniform: VyT[m][k], oxT[m][k]
// (contiguous 64-float rows -> scalar loads). No LDS, no barriers.
__global__ __launch_bounds__(256) void k_inv2(const float* __restrict__ oy,
    const float* __restrict__ oxT, const float* __restrict__ VyT,
    const float* __restrict__ Vx, const float* __restrict__ b1,
    float* __restrict__ x2){
  int bx = blockIdx.x;
  int strip = bx % 6; int o = (bx/6) & 31; int bb = bx/192;
  int tid = threadIdx.x;
  int lane = tid & 63;
  int m0 = __builtin_amdgcn_readfirstlane((tid >> 6)*45);   // wave-uniform m-base
  int n = strip*64 + lane;
  bool nval = n < NSX;
  int nc2 = (nval ? n : (NSX-1))*2;
  float oyR[32], oyI[32], vxR[32], vxI[32];
  const float* oyb = oy + (size_t)(bb*NW + o)*NMODES*(NSX*2);
  #pragma unroll
  for (int k=0;k<32;k++){
    float2 t = *(const float2*)&oyb[k*(NSX*2) + nc2];
    oyR[k]=t.x; oyI[k]=t.y;
    float2 v = *(const float2*)&Vx[k*(NSX*2) + nc2];
    vxR[k]=v.x; vxI[k]=v.y;
  }
  const float* oxb = oxT + (size_t)(bb*NW + o)*NSY*64;
  float b1v = b1[o];
  float* xout = x2 + (size_t)(bb*NW + o)*NPIX;
  for (int mi=0; mi<45; mi++){
    int m = m0 + mi;
    const float* vyr = VyT + (size_t)m*64;   // uniform row, 64 contiguous floats
    const float* oxr = oxb + (size_t)m*64;   // uniform row, 64 contiguous floats
    float a = b1v;
    #pragma unroll
    for (int k=0;k<32;k++){
      a += vyr[k*2]*oyR[k] + vyr[k*2+1]*oyI[k]
         + oxr[k*2]*vxR[k] + oxr[k*2+1]*vxI[k];
    }
    if (nval) xout[m*NSX + n] = a;
  }
}

// ---------------- pointwise: h += (gelu?)(W2 @ gelu(x2) + b2) ----------------
__global__ __launch_bounds__(256) void k_pw(const float* __restrict__ x2,
    const float* __restrict__ w2m, const float* __restrict__ b2,
    float* __restrict__ h, int last, int b0, int nloc){
  int p = blockIdx.x*256 + threadIdx.x;
  if (p >= nloc*NPIX) return;
  int bb = p/NPIX, r = p%NPIX;
  const float* xb = x2 + (size_t)bb*NW*NPIX + r;
  float t[NW];
  #pragma unroll
  for (int c=0;c<NW;c++) t[c] = gelu_f(xb[(size_t)c*NPIX]);
  float* hb = h + (size_t)(b0+bb)*NW*NPIX + r;
  for (int o=0;o<NW;o++){
    float a = b2[o];
    #pragma unroll
    for (int c=0;c<NW;c++) a += t[c]*w2m[o*32+c];
    float g = last ? a : gelu_f(a);
    hb[(size_t)o*NPIX] += g;
  }
}

// ---------------- fc1 + gelu + fc2 ----------------
__global__ __launch_bounds__(256) void k_fc12(const float* __restrict__ h,
    const float* __restrict__ f1T, const float* __restrict__ f1b,
    const float* __restrict__ f2w, const float* __restrict__ f2b,
    float* __restrict__ out){
  int p = blockIdx.x*256 + threadIdx.x;
  if (p >= NPTS) return;
  int b = p/NPIX, r = p%NPIX;
  const float* hb = h + (size_t)b*NW*NPIX + r;
  float t[NW];
  #pragma unroll
  for (int c=0;c<NW;c++) t[c] = hb[(size_t)c*NPIX];
  float acc = f2b[0];
  for (int j=0;j<128;j++){
    float s = f1b[j];
    const float* wr = f1T + j*32;
    #pragma unroll
    for (int c=0;c<NW;c++) s += t[c]*wr[c];
    acc += gelu_f(s)*f2w[j];
  }
  out[p] = acc;
}

extern "C" void kernel_launch(void* const* d_in, const int* in_sizes, int n_in,
                              void* d_out, int out_size, void* d_ws, size_t ws_size,
                              hipStream_t stream) {
  const float* x     = (const float*)d_in[0];
  const float* sx    = (const float*)d_in[1];
  const float* sy    = (const float*)d_in[2];
  const float* fc0_w = (const float*)d_in[3];
  const float* fc0_b = (const float*)d_in[4];
  const float* fw1   = (const float*)d_in[5];
  const float* fw2   = (const float*)d_in[6];
  const float* w1m   = (const float*)d_in[7];
  const float* b1    = (const float*)d_in[8];
  const float* w2m   = (const float*)d_in[9];
  const float* b2    = (const float*)d_in[10];
  const float* fc1_w = (const float*)d_in[11];
  const float* fc1_b = (const float*)d_in[12];
  const float* fc2_w = (const float*)d_in[13];
  const float* fc2_b = (const float*)d_in[14];
  float* out = (float*)d_out;

  float* ws = (float*)d_ws;
  size_t off = 0;
  float* h   = ws + off; off += SZ_H;
  float* Vy  = ws + off; off += SZ_VY;
  float* Vx  = ws + off; off += SZ_VX;
  float* VyT = ws + off; off += SZ_VYT;
  float* gx  = ws + off; off += SZ_GX;
  float* gy  = ws + off; off += SZ_GY;
  float* w1f = ws + off; off += SZ_W1F;
  float* w2f = ws + off; off += SZ_W2F;
  float* f1T = ws + off; off += SZ_F1T;
  const size_t fixed = off;
  const size_t per_batch = (size_t)SZ_X2FT_PB + SZ_OY_PB + SZ_OX_PB;  // 3,179,520 floats

  // largest batch-chunk NC that fits ws (ws_size constant across calls -> graph-safe)
  int NC = 16;
  for (; NC > 1; NC >>= 1) {
    if ((fixed + (size_t)NC*per_batch)*sizeof(float) <= ws_size) break;
  }
  float* x2ft = ws + fixed;                // ft lives here until k_inv2 overwrites with x2
  float* oy   = x2ft + (size_t)NC*SZ_X2FT_PB;
  float* ox   = oy   + (size_t)NC*SZ_OY_PB;

  k_prep<<<45, 256, 0, stream>>>(sx, sy, fc1_w, Vy, Vx, VyT, gx, gy, f1T);
  k_fold<<<1024, 256, 0, stream>>>(fw1, fw2, w1m, w1f, w2f);
  k_fc0<<<4050, 256, 0, stream>>>(x, gx, gy, fc0_w, fc0_b, h);

  for (int i=0;i<4;i++){
    for (int b0=0; b0<NB; b0+=NC){
      k_fwd_y<<<NC*192, 256, 0, stream>>>(h, Vy, x2ft, b0);
      k_mix<<<NC*64, 192, 0, stream>>>(x2ft, w1f + (size_t)i*65536, oy, NSX, 2, 0);
      k_fwd_x<<<NC*96, 256, 0, stream>>>(h, Vx, x2ft, b0);
      k_mix<<<NC*32, 192, 0, stream>>>(x2ft, w2f + (size_t)i*65536, ox, NSY, 1, 1);
      k_inv2<<<NC*192, 256, 0, stream>>>(oy, ox, VyT, Vx, b1 + i*32, x2ft);
      k_pw<<<(NC*NPIX + 255)/256, 256, 0, stream>>>(x2ft, w2m + (size_t)i*1024,
                                                    b2 + i*32, h, (int)(i==3), b0, NC);
    }
  }

  k_fc12<<<4050, 256, 0, stream>>>(h, f1T, fc1_b, fc2_w, fc2_b, out);
}

// Round 5
// 2448.104 us; speedup vs baseline: 11.8906x; 1.3987x over previous
//
#include <hip/hip_runtime.h>
#include <math.h>

#define NB 16
#define NSY 180
#define NSX 360
#define NCIN 16
#define NW 32
#define NMODES 32
#define NPIX (NSY*NSX)     // 64800
#define NPTS (NB*NPIX)     // 1036800

typedef unsigned int uint;
typedef unsigned short ushort;
typedef __attribute__((ext_vector_type(8))) short bf16x8;
typedef __attribute__((ext_vector_type(4))) float f32x4;

union U4 { uint u[4]; bf16x8 v; };

__device__ __forceinline__ float gelu_f(float v){
  return 0.5f*v*(1.0f + erff(v*0.70710678118654752440f));
}
__device__ __forceinline__ ushort f2bf(float x){
  uint u = __float_as_uint(x);
  return (ushort)((u + 0x7FFFu + ((u>>16)&1u)) >> 16);
}
__device__ __forceinline__ uint packbf2(float a, float b){
  return (uint)f2bf(a) | ((uint)f2bf(b) << 16);
}
__device__ __forceinline__ float bf2f(ushort u){
  return __uint_as_float(((uint)u) << 16);
}

// ---------------- prep: bf16 Vandermonde matrices (zero-padded), grid, fc1^T ----------------
// Abfy [64 kri][192 m], Abfx [64 kri][384 n], VyCT [192 m][64 kri], VxCT [384 n][64 kri]
__global__ __launch_bounds__(256) void k_prep(const float* __restrict__ sx,
    const float* __restrict__ sy, const float* __restrict__ fc1_w,
    ushort* __restrict__ Abfy, ushort* __restrict__ Abfx,
    ushort* __restrict__ VyCT, ushort* __restrict__ VxCT,
    ushort* __restrict__ f1Tbf, float* __restrict__ gx, float* __restrict__ gy){
  int idx = blockIdx.x*256 + threadIdx.x;
  float sx0 = sx[0], sxL = sx[NSX-1];
  float sy0 = sy[0], syL = sy[NSY-1];
  const float scy = 0.07453559924999298980f;   // 1/sqrt(180)
  const float scx = 0.05270462766947298886f;   // 1/sqrt(360)
  if (idx < NSX) gx[idx] = (sx[idx]-sx0)/sxL;
  if (idx < NSY) gy[idx] = (sy[idx]-sy0)/syL;
  if (idx < 64*192){
    int kri = idx/192, m = idx%192;
    float val = 0.f;
    if (m < NSY){
      int k = kri>>1;
      float p = (sy[m]-sy0)/(syL-sy0);
      float ang = -6.2831853071795864769f*(float)k*p;
      val = ((kri&1)? sinf(ang) : cosf(ang))*scy;
    }
    Abfy[idx] = f2bf(val);
  }
  if (idx < 192*64){
    int m = idx/64, kri = idx%64;
    float val = 0.f;
    if (m < NSY){
      int k = kri>>1;
      float p = (sy[m]-sy0)/(syL-sy0);
      float ang = -6.2831853071795864769f*(float)k*p;
      val = ((kri&1)? sinf(ang) : cosf(ang))*scy;
    }
    VyCT[idx] = f2bf(val);
  }
  if (idx < 64*384){
    int kri = idx/384, n = idx%384;
    float val = 0.f;
    if (n < NSX){
      int k = kri>>1;
      float p = (sx[n]-sx0)/(sxL-sx0);
      float ang = -6.2831853071795864769f*(float)k*p;
      val = ((kri&1)? sinf(ang) : cosf(ang))*scx;
    }
    Abfx[idx] = f2bf(val);
  }
  if (idx < 384*64){
    int n = idx/64, kri = idx%64;
    float val = 0.f;
    if (n < NSX){
      int k = kri>>1;
      float p = (sx[n]-sx0)/(sxL-sx0);
      float ang = -6.2831853071795864769f*(float)k*p;
      val = ((kri&1)? sinf(ang) : cosf(ang))*scx;
    }
    VxCT[idx] = f2bf(val);
  }
  if (idx < 128*32){
    int j = idx >> 5, c = idx & 31;
    f1Tbf[idx] = f2bf(fc1_w[c*128 + j]);
  }
}

// ---------------- fold pointwise w1 into the mode-mix weights ----------------
__global__ __launch_bounds__(256) void k_fold(const float* __restrict__ fw1,
    const float* __restrict__ fw2, const float* __restrict__ w1m,
    float* __restrict__ w1f, float* __restrict__ w2f){
  int id = blockIdx.x*256 + threadIdx.x;      // 0..262143
  int half = id >> 17;
  int r = id & 131071;
  int i  = r >> 15;
  int in = (r >> 10) & 31;
  int k  = (r >> 5) & 31;
  int o  = r & 31;
  const float* src = half ? fw2 : fw1;
  const float* wm  = w1m + i*1024 + o*32;
  const float* sp  = src + ((size_t)((i*32+in)*1024 + k))*2;
  float sR = 0.f, sI = 0.f;
  #pragma unroll
  for (int c=0;c<32;c++){
    float w = wm[c];
    sR += w * sp[c*64];
    sI += w * sp[c*64+1];
  }
  float* dst = half ? w2f : w1f;
  size_t oi = ((size_t)((i*32+in)*32 + k)*32 + o)*2;
  dst[oi] = sR; dst[oi+1] = sI;
}

// ---------------- fc0 ----------------
__global__ __launch_bounds__(256) void k_fc0(const float* __restrict__ x,
    const float* __restrict__ gx, const float* __restrict__ gy,
    const float* __restrict__ fw, const float* __restrict__ fb,
    float* __restrict__ h){
  int p = blockIdx.x*256 + threadIdx.x;
  if (p >= NPTS) return;
  int b = p/NPIX, r = p%NPIX, m = r/NSX, n = r%NSX;
  const float* xp = x + (size_t)p*NCIN;
  float xv[NCIN+2];
  #pragma unroll
  for (int j=0;j<NCIN;j++) xv[j] = xp[j];
  xv[16] = gx[n]; xv[17] = gy[m];
  float acc[NW];
  #pragma unroll
  for (int o=0;o<NW;o++) acc[o] = fb[o];
  #pragma unroll
  for (int j=0;j<NCIN+2;j++){
    float v = xv[j];
    #pragma unroll
    for (int o=0;o<NW;o++) acc[o] += v*fw[j*32+o];
  }
  float* hp = h + (size_t)b*NW*NPIX + r;
  #pragma unroll
  for (int o=0;o<NW;o++) hp[(size_t)o*NPIX] = acc[o];
}

// ---------------- MFMA forward DFT over y: fty[bb][c][kri][n] = (Abfy x h) ----------------
// GEMM M=64(kri), N=64(n-tile), K=192(m pad). Per block: (bb, c, n-tile).
__global__ __launch_bounds__(256) void k_fwdy(const float* __restrict__ h,
    const ushort* __restrict__ Abfy, ushort* __restrict__ fty, int b0){
  __shared__ uint Bt[64*18];     // [n_local][m-pair], stride 18 dwords
  int bx = blockIdx.x;
  int nt6 = bx % 6; int c = (bx/6) & 31; int bb = bx/192;
  int n0 = nt6*64;
  int tid = threadIdx.x;
  int l = tid & 63, g = tid >> 6;
  int c15 = l & 15, q = l >> 4;
  const float* hb = h + (size_t)((b0+bb)*NW + c)*NPIX;
  bf16x8 afr[6];
  #pragma unroll
  for (int ks=0; ks<6; ks++)
    afr[ks] = *(const bf16x8*)(Abfy + (size_t)(16*g + c15)*192 + ks*32 + q*8);
  f32x4 acc[4];
  #pragma unroll
  for (int t=0;t<4;t++) acc[t] = (f32x4){0.f,0.f,0.f,0.f};
  int n = n0 + l;
  bool nv = n < NSX;
  for (int ks=0; ks<6; ks++){
    __syncthreads();
    float v[8];
    #pragma unroll
    for (int j=0;j<8;j++){
      int m = ks*32 + 8*g + j;
      v[j] = (nv && m < NSY) ? hb[(size_t)m*NSX + n] : 0.f;
    }
    #pragma unroll
    for (int i=0;i<4;i++)
      Bt[l*18 + 4*g + i] = packbf2(v[2*i], v[2*i+1]);
    __syncthreads();
    #pragma unroll
    for (int nt=0; nt<4; nt++){
      const uint* bp = &Bt[(nt*16 + c15)*18 + q*4];
      U4 bu;
      uint2 lo = *(const uint2*)(bp);
      uint2 hi = *(const uint2*)(bp+2);
      bu.u[0]=lo.x; bu.u[1]=lo.y; bu.u[2]=hi.x; bu.u[3]=hi.y;
      acc[nt] = __builtin_amdgcn_mfma_f32_16x16x32_bf16(afr[ks], bu.v, acc[nt], 0,0,0);
    }
  }
  ushort* fb = fty + (size_t)(bb*NW + c)*64*NSX;
  #pragma unroll
  for (int nt=0; nt<4; nt++){
    int nn = n0 + nt*16 + c15;
    if (nn < NSX){
      #pragma unroll
      for (int r=0;r<4;r++){
        int kri = 16*g + q*4 + r;
        fb[(size_t)kri*NSX + nn] = f2bf(acc[nt][r]);
      }
    }
  }
}

// ---------------- MFMA forward DFT over x: ftx[bb][c][kri][m] ----------------
// GEMM M=64(kri), N=64(m-tile), K=384(n pad). Per block: (bb, c, m-tile of 3).
__global__ __launch_bounds__(256) void k_fwdx(const float* __restrict__ h,
    const ushort* __restrict__ Abfx, ushort* __restrict__ ftx, int b0){
  __shared__ uint Bt[64*18];     // [m_local][n-pair]
  int bx = blockIdx.x;
  int mt = bx % 3; int c = (bx/3) & 31; int bb = bx/96;
  int m0 = mt*64;
  int tid = threadIdx.x;
  int l = tid & 63, g = tid >> 6;
  int c15 = l & 15, q = l >> 4;
  const float* hb = h + (size_t)((b0+bb)*NW + c)*NPIX;
  bf16x8 afr[12];
  #pragma unroll
  for (int ks=0; ks<12; ks++)
    afr[ks] = *(const bf16x8*)(Abfx + (size_t)(16*g + c15)*384 + ks*32 + q*8);
  f32x4 acc[4];
  #pragma unroll
  for (int t=0;t<4;t++) acc[t] = (f32x4){0.f,0.f,0.f,0.f};
  int m = m0 + l;
  bool mv = m < NSY;
  for (int ks=0; ks<12; ks++){
    __syncthreads();
    int nb2 = ks*32 + 8*g;
    float4 p0 = {0.f,0.f,0.f,0.f}, p1 = {0.f,0.f,0.f,0.f};
    if (mv && nb2 < NSX){
      p0 = *(const float4*)(hb + (size_t)m*NSX + nb2);
      p1 = *(const float4*)(hb + (size_t)m*NSX + nb2 + 4);
    }
    Bt[l*18 + 4*g + 0] = packbf2(p0.x, p0.y);
    Bt[l*18 + 4*g + 1] = packbf2(p0.z, p0.w);
    Bt[l*18 + 4*g + 2] = packbf2(p1.x, p1.y);
    Bt[l*18 + 4*g + 3] = packbf2(p1.z, p1.w);
    __syncthreads();
    #pragma unroll
    for (int nt=0; nt<4; nt++){
      const uint* bp = &Bt[(nt*16 + c15)*18 + q*4];
      U4 bu;
      uint2 lo = *(const uint2*)(bp);
      uint2 hi = *(const uint2*)(bp+2);
      bu.u[0]=lo.x; bu.u[1]=lo.y; bu.u[2]=hi.x; bu.u[3]=hi.y;
      acc[nt] = __builtin_amdgcn_mfma_f32_16x16x32_bf16(afr[ks], bu.v, acc[nt], 0,0,0);
    }
  }
  ushort* fb = ftx + (size_t)(bb*NW + c)*64*NSY;
  #pragma unroll
  for (int nt=0; nt<4; nt++){
    int mm = m0 + nt*16 + c15;
    if (mm < NSY){
      #pragma unroll
      for (int r=0;r<4;r++){
        int kri = 16*g + q*4 + r;
        fb[(size_t)kri*NSY + mm] = f2bf(acc[nt][r]);
      }
    }
  }
}

// ---------------- per-mode complex channel mix, bf16 planar I/O ----------------
// oo[bb][o][kri][n] = sum_in ft[bb][in][kri][n] (complex) * wf[in][k][o] (complex)
__global__ __launch_bounds__(192) void k_mix(const ushort* __restrict__ ft,
    const float* __restrict__ wf, ushort* __restrict__ oo, int Nlen, int ntiles){
  int bx = blockIdx.x;
  int nt = bx % ntiles; int k = (bx/ntiles) & 31; int b = bx/(ntiles*32);
  int tid = threadIdx.x;
  int n = nt*192 + tid;
  bool valid = n < Nlen;
  int nn = valid ? n : (Nlen-1);
  const ushort* fb = ft + (size_t)(b*NW)*64*Nlen + (size_t)(2*k)*Nlen + nn;
  const float* wb = wf + (size_t)k*64;
  float aR[32], aI[32];
  #pragma unroll
  for (int o=0;o<32;o++){ aR[o]=0.f; aI[o]=0.f; }
  for (int in=0; in<32; in++){
    float fR = bf2f(fb[(size_t)in*64*Nlen]);
    float fI = bf2f(fb[(size_t)in*64*Nlen + Nlen]);
    const float* wrow = wb + in*2048;
    #pragma unroll
    for (int o=0;o<32;o++){
      float wR = wrow[o*2], wI = wrow[o*2+1];
      aR[o] += fR*wR - fI*wI;
      aI[o] += fR*wI + fI*wR;
    }
  }
  if (valid){
    ushort* ob = oo + (size_t)(b*NW)*64*Nlen + (size_t)(2*k)*Nlen + n;
    #pragma unroll
    for (int o=0;o<32;o++){
      ob[(size_t)o*64*Nlen]        = f2bf(aR[o]);
      ob[(size_t)o*64*Nlen + Nlen] = f2bf(aI[o]);
    }
  }
}

// ---------------- MFMA inverse (y+x combined): x2[bb][o][m][n] ----------------
// C[m][n] = [VyCT | oxT](m x 128k) x [oy ; VxC](128k x n), + b1.
__global__ __launch_bounds__(256) void k_inv(const ushort* __restrict__ oyb,
    const ushort* __restrict__ oxb, const ushort* __restrict__ VyCT,
    const ushort* __restrict__ VxCT, const float* __restrict__ b1,
    float* __restrict__ x2){
  __shared__ uint At[64*34];     // [m_local][kri-pair 0..31]
  __shared__ uint Bt[64*34];     // [n_local][kri-pair 0..31]
  int bx = blockIdx.x;
  int nt6 = bx % 6; int mt = (bx/6) % 3; int o = (bx/18) & 31; int bb = bx/576;
  int m0 = mt*64, n0 = nt6*64;
  int tid = threadIdx.x;
  int l = tid & 63, g = tid >> 6;
  int c15 = l & 15, q = l >> 4;
  const ushort* oxp = oxb + (size_t)(bb*NW + o)*64*NSY;
  const ushort* oyp = oyb + (size_t)(bb*NW + o)*64*NSX;
  {
    int m = m0 + l; bool mv = m < NSY;
    #pragma unroll
    for (int i=0;i<8;i++){
      int kri0 = 16*g + 2*i;
      ushort a = mv ? oxp[(size_t)kri0*NSY + m] : (ushort)0;
      ushort b = mv ? oxp[(size_t)(kri0+1)*NSY + m] : (ushort)0;
      At[l*34 + 8*g + i] = (uint)a | ((uint)b << 16);
    }
    int n = n0 + l; bool nv = n < NSX;
    #pragma unroll
    for (int i=0;i<8;i++){
      int kri0 = 16*g + 2*i;
      ushort a = nv ? oyp[(size_t)kri0*NSX + n] : (ushort)0;
      ushort b = nv ? oyp[(size_t)(kri0+1)*NSX + n] : (ushort)0;
      Bt[l*34 + 8*g + i] = (uint)a | ((uint)b << 16);
    }
  }
  __syncthreads();
  bf16x8 afr[4];
  afr[0] = *(const bf16x8*)(VyCT + (size_t)(m0 + 16*g + c15)*64 + q*8);
  afr[1] = *(const bf16x8*)(VyCT + (size_t)(m0 + 16*g + c15)*64 + 32 + q*8);
  {
    const uint* ap = &At[(16*g + c15)*34 + q*4];
    U4 au; uint2 lo = *(const uint2*)ap; uint2 hi = *(const uint2*)(ap+2);
    au.u[0]=lo.x; au.u[1]=lo.y; au.u[2]=hi.x; au.u[3]=hi.y;
    afr[2] = au.v;
    const uint* ap2 = &At[(16*g + c15)*34 + 16 + q*4];
    U4 au2; uint2 lo2 = *(const uint2*)ap2; uint2 hi2 = *(const uint2*)(ap2+2);
    au2.u[0]=lo2.x; au2.u[1]=lo2.y; au2.u[2]=hi2.x; au2.u[3]=hi2.y;
    afr[3] = au2.v;
  }
  f32x4 acc[4];
  #pragma unroll
  for (int t=0;t<4;t++) acc[t] = (f32x4){0.f,0.f,0.f,0.f};
  #pragma unroll
  for (int nt=0; nt<4; nt++){
    int nb = n0 + nt*16 + c15;
    const uint* bp = &Bt[(nt*16 + c15)*34 + q*4];
    U4 b0u; { uint2 lo = *(const uint2*)bp; uint2 hi = *(const uint2*)(bp+2);
      b0u.u[0]=lo.x; b0u.u[1]=lo.y; b0u.u[2]=hi.x; b0u.u[3]=hi.y; }
    const uint* bp1 = &Bt[(nt*16 + c15)*34 + 16 + q*4];
    U4 b1u; { uint2 lo = *(const uint2*)bp1; uint2 hi = *(const uint2*)(bp1+2);
      b1u.u[0]=lo.x; b1u.u[1]=lo.y; b1u.u[2]=hi.x; b1u.u[3]=hi.y; }
    bf16x8 b2f = *(const bf16x8*)(VxCT + (size_t)nb*64 + q*8);
    bf16x8 b3f = *(const bf16x8*)(VxCT + (size_t)nb*64 + 32 + q*8);
    acc[nt] = __builtin_amdgcn_mfma_f32_16x16x32_bf16(afr[0], b0u.v, acc[nt], 0,0,0);
    acc[nt] = __builtin_amdgcn_mfma_f32_16x16x32_bf16(afr[1], b1u.v, acc[nt], 0,0,0);
    acc[nt] = __builtin_amdgcn_mfma_f32_16x16x32_bf16(afr[2], b2f, acc[nt], 0,0,0);
    acc[nt] = __builtin_amdgcn_mfma_f32_16x16x32_bf16(afr[3], b3f, acc[nt], 0,0,0);
  }
  float bias = b1[o];
  float* xp = x2 + (size_t)(bb*NW + o)*NPIX;
  #pragma unroll
  for (int nt=0; nt<4; nt++){
    int n = n0 + nt*16 + c15;
    if (n < NSX){
      #pragma unroll
      for (int r=0;r<4;r++){
        int m = m0 + 16*g + q*4 + r;
        if (m < NSY) xp[(size_t)m*NSX + n] = acc[nt][r] + bias;
      }
    }
  }
}

// ---------------- pointwise: h += (gelu?)(W2 @ gelu(x2) + b2); last iter -> hT bf16 ----------------
__global__ __launch_bounds__(256) void k_pw(const float* __restrict__ x2,
    const float* __restrict__ w2m, const float* __restrict__ b2,
    float* __restrict__ h, ushort* __restrict__ hT, int last, int b0, int nloc){
  int p = blockIdx.x*256 + threadIdx.x;
  if (p >= nloc*NPIX) return;
  int bb = p/NPIX, r = p%NPIX;
  const float* xb = x2 + (size_t)bb*NW*NPIX + r;
  float t[NW];
  #pragma unroll
  for (int c=0;c<NW;c++) t[c] = gelu_f(xb[(size_t)c*NPIX]);
  float* hb = h + (size_t)(b0+bb)*NW*NPIX + r;
  uint* hp = (uint*)(hT + ((size_t)(b0+bb)*NPIX + r)*32);
  for (int o=0;o<NW;o+=2){
    float a0 = b2[o], a1 = b2[o+1];
    #pragma unroll
    for (int c=0;c<NW;c++){
      a0 += t[c]*w2m[o*32+c];
      a1 += t[c]*w2m[(o+1)*32+c];
    }
    if (!last){
      hb[(size_t)o*NPIX]     += gelu_f(a0);
      hb[(size_t)(o+1)*NPIX] += gelu_f(a1);
    } else {
      float v0 = hb[(size_t)o*NPIX] + a0;
      float v1 = hb[(size_t)(o+1)*NPIX] + a1;
      hp[o>>1] = packbf2(v0, v1);
    }
  }
}

// ---------------- MFMA fc1 + gelu + fc2 ----------------
__global__ __launch_bounds__(256) void k_fc12m(const ushort* __restrict__ hT,
    const ushort* __restrict__ f1Tbf, const float* __restrict__ f1b,
    const float* __restrict__ f2w, const float* __restrict__ f2b,
    float* __restrict__ out){
  int blk = blockIdx.x; int tid = threadIdx.x;
  int g = tid >> 6, lane = tid & 63;
  int c15 = lane & 15, q = lane >> 4;
  int pbase = blk*64 + g*16;
  bf16x8 afr = *(const bf16x8*)(hT + (size_t)(pbase + c15)*32 + q*8);
  f32x4 acc[8];
  #pragma unroll
  for (int t=0;t<8;t++) acc[t] = (f32x4){0.f,0.f,0.f,0.f};
  #pragma unroll
  for (int nt=0; nt<8; nt++){
    bf16x8 bfr = *(const bf16x8*)(f1Tbf + (size_t)(nt*16 + c15)*32 + q*8);
    acc[nt] = __builtin_amdgcn_mfma_f32_16x16x32_bf16(afr, bfr, acc[nt], 0,0,0);
  }
  float s[4] = {0.f,0.f,0.f,0.f};
  #pragma unroll
  for (int nt=0; nt<8; nt++){
    int j = nt*16 + c15;
    float bj = f1b[j], wj = f2w[j];
    #pragma unroll
    for (int r=0;r<4;r++) s[r] += gelu_f(acc[nt][r] + bj) * wj;
  }
  #pragma unroll
  for (int msk=1; msk<16; msk<<=1){
    #pragma unroll
    for (int r=0;r<4;r++) s[r] += __shfl_xor(s[r], msk, 64);
  }
  if (c15 == 0){
    float fb2 = f2b[0];
    float4 v = {s[0]+fb2, s[1]+fb2, s[2]+fb2, s[3]+fb2};
    *(float4*)(out + pbase + q*4) = v;
  }
}

extern "C" void kernel_launch(void* const* d_in, const int* in_sizes, int n_in,
                              void* d_out, int out_size, void* d_ws, size_t ws_size,
                              hipStream_t stream) {
  const float* x     = (const float*)d_in[0];
  const float* sx    = (const float*)d_in[1];
  const float* sy    = (const float*)d_in[2];
  const float* fc0_w = (const float*)d_in[3];
  const float* fc0_b = (const float*)d_in[4];
  const float* fw1   = (const float*)d_in[5];
  const float* fw2   = (const float*)d_in[6];
  const float* w1m   = (const float*)d_in[7];
  const float* b1    = (const float*)d_in[8];
  const float* w2m   = (const float*)d_in[9];
  const float* b2    = (const float*)d_in[10];
  const float* fc1_w = (const float*)d_in[11];
  const float* fc1_b = (const float*)d_in[12];
  const float* fc2_w = (const float*)d_in[13];
  const float* fc2_b = (const float*)d_in[14];
  float* out = (float*)d_out;

  char* wsb = (char*)d_ws;
  size_t off = 0;
  auto alloc = [&](size_t bytes)->char*{
    char* p = wsb + off;
    off = (off + bytes + 255) & ~(size_t)255;
    return p;
  };
  float*  h     = (float*)alloc((size_t)NB*NW*NPIX*4);   // 132,710,400
  ushort* Abfy  = (ushort*)alloc(64*192*2);
  ushort* Abfx  = (ushort*)alloc(64*384*2);
  ushort* VyCT  = (ushort*)alloc(192*64*2);
  ushort* VxCT  = (ushort*)alloc(384*64*2);
  ushort* f1Tbf = (ushort*)alloc(128*32*2);
  float*  gx    = (float*)alloc(NSX*4);
  float*  gy    = (float*)alloc(NSY*4);
  float*  w1f   = (float*)alloc(262144*4);
  float*  w2f   = (float*)alloc(262144*4);
  const size_t fixedB = off;

  const size_t szX2  = (size_t)NW*NPIX*4;     // 8,294,400
  const size_t szFty = (size_t)NW*64*NSX*2;   // 1,474,560
  const size_t szFtx = (size_t)NW*64*NSY*2;   // 737,280
  const size_t szOy  = szFty, szOx = szFtx;
  const size_t perB  = szX2 + szFty + szFtx + szOy + szOx;
  const size_t szHT  = (size_t)NPTS*NW*2;     // 66,355,200

  int NC = 16;
  while (NC > 1){
    size_t need = fixedB + (size_t)NC*perB + ((NC==16)? 0 : szHT) + 4096;
    if (need <= ws_size) break;
    NC >>= 1;
  }
  char* pb = wsb + fixedB;
  float*  x2  = (float*)pb;
  ushort* fty = (ushort*)(pb + (size_t)NC*szX2);
  ushort* ftx = (ushort*)((char*)fty + (size_t)NC*szFty);
  ushort* oy  = (ushort*)((char*)ftx + (size_t)NC*szFtx);
  ushort* ox  = (ushort*)((char*)oy  + (size_t)NC*szOy);
  // hT (bf16 [NPTS][32]) aliases the spectral scratch at NC=16 (all dead by then);
  // at NC<16 it gets its own region after ox.
  ushort* hT  = (NC==16) ? fty : (ushort*)((char*)ox + (size_t)NC*szOx);

  k_prep<<<96, 256, 0, stream>>>(sx, sy, fc1_w, Abfy, Abfx, VyCT, VxCT, f1Tbf, gx, gy);
  k_fold<<<1024, 256, 0, stream>>>(fw1, fw2, w1m, w1f, w2f);
  k_fc0<<<4050, 256, 0, stream>>>(x, gx, gy, fc0_w, fc0_b, h);

  for (int i=0;i<4;i++){
    for (int b0=0; b0<NB; b0+=NC){
      k_fwdy<<<NC*192, 256, 0, stream>>>(h, Abfy, fty, b0);
      k_mix<<<NC*64, 192, 0, stream>>>(fty, w1f + (size_t)i*65536, oy, NSX, 2);
      k_fwdx<<<NC*96, 256, 0, stream>>>(h, Abfx, ftx, b0);
      k_mix<<<NC*32, 192, 0, stream>>>(ftx, w2f + (size_t)i*65536, ox, NSY, 1);
      k_inv<<<NC*576, 256, 0, stream>>>(oy, ox, VyCT, VxCT, b1 + i*32, x2);
      k_pw<<<(NC*NPIX + 255)/256, 256, 0, stream>>>(x2, w2m + (size_t)i*1024,
                                                    b2 + i*32, h, hT, (int)(i==3), b0, NC);
    }
  }

  k_fc12m<<<NPTS/64, 256, 0, stream>>>(hT, f1Tbf, fc1_b, fc2_w, fc2_b, out);
}

// Round 7
// 1284.703 us; speedup vs baseline: 22.6584x; 1.9056x over previous
//
#include <hip/hip_runtime.h>
#include <math.h>

#define NB 16
#define NSY 180
#define NSX 360
#define NCIN 16
#define NW 32
#define NMODES 32
#define NPIX (NSY*NSX)     // 64800
#define NPTS (NB*NPIX)     // 1036800

typedef unsigned int uint;
typedef unsigned short ushort;
typedef __attribute__((ext_vector_type(8))) short bf16x8;
typedef __attribute__((ext_vector_type(4))) float f32x4;

union U4 { uint u[4]; bf16x8 v; };

// tanh-gelu: v*sigmoid(1.5957691*(v + 0.044715 v^3)); max dev vs erf-gelu ~3e-4
__device__ __forceinline__ float gelu_f(float v){
  float u = v*(-1.5957691216f - 0.0713548163f*v*v);
  return v / (1.f + __expf(u));
}
__device__ __forceinline__ ushort f2bf(float x){
  uint u = __float_as_uint(x);
  return (ushort)((u + 0x7FFFu + ((u>>16)&1u)) >> 16);
}
__device__ __forceinline__ uint packbf2(float a, float b){
  return (uint)f2bf(a) | ((uint)f2bf(b) << 16);
}
__device__ __forceinline__ float bf2f(ushort u){
  return __uint_as_float(((uint)u) << 16);
}

// ---------------- prep: bf16 Vandermonde (zero-padded), grid, fc1^T ----------------
// Abfy [64 kri][192 m], Abfx [64 kri][384 n], VyCT [192 m][64 kri], VxCT [384 n][64 kri]
__global__ __launch_bounds__(256) void k_prep(const float* __restrict__ sx,
    const float* __restrict__ sy, const float* __restrict__ fc1_w,
    ushort* __restrict__ Abfy, ushort* __restrict__ Abfx,
    ushort* __restrict__ VyCT, ushort* __restrict__ VxCT,
    ushort* __restrict__ f1Tbf, float* __restrict__ gx, float* __restrict__ gy){
  int idx = blockIdx.x*256 + threadIdx.x;
  float sx0 = sx[0], sxL = sx[NSX-1];
  float sy0 = sy[0], syL = sy[NSY-1];
  const float scy = 0.07453559924999298980f;   // 1/sqrt(180)
  const float scx = 0.05270462766947298886f;   // 1/sqrt(360)
  if (idx < NSX) gx[idx] = (sx[idx]-sx0)/sxL;
  if (idx < NSY) gy[idx] = (sy[idx]-sy0)/syL;
  if (idx < 64*192){
    int kri = idx/192, m = idx%192;
    float val = 0.f;
    if (m < NSY){
      int k = kri>>1;
      float p = (sy[m]-sy0)/(syL-sy0);
      float ang = -6.2831853071795864769f*(float)k*p;
      val = ((kri&1)? sinf(ang) : cosf(ang))*scy;
    }
    Abfy[idx] = f2bf(val);
  }
  if (idx < 192*64){
    int m = idx/64, kri = idx%64;
    float val = 0.f;
    if (m < NSY){
      int k = kri>>1;
      float p = (sy[m]-sy0)/(syL-sy0);
      float ang = -6.2831853071795864769f*(float)k*p;
      val = ((kri&1)? sinf(ang) : cosf(ang))*scy;
    }
    VyCT[idx] = f2bf(val);
  }
  if (idx < 64*384){
    int kri = idx/384, n = idx%384;
    float val = 0.f;
    if (n < NSX){
      int k = kri>>1;
      float p = (sx[n]-sx0)/(sxL-sx0);
      float ang = -6.2831853071795864769f*(float)k*p;
      val = ((kri&1)? sinf(ang) : cosf(ang))*scx;
    }
    Abfx[idx] = f2bf(val);
  }
  if (idx < 384*64){
    int n = idx/64, kri = idx%64;
    float val = 0.f;
    if (n < NSX){
      int k = kri>>1;
      float p = (sx[n]-sx0)/(sxL-sx0);
      float ang = -6.2831853071795864769f*(float)k*p;
      val = ((kri&1)? sinf(ang) : cosf(ang))*scx;
    }
    VxCT[idx] = f2bf(val);
  }
  if (idx < 128*32){
    int j = idx >> 5, c = idx & 31;
    f1Tbf[idx] = f2bf(fc1_w[c*128 + j]);
  }
}

// ---------------- fold pointwise w1 into the mode-mix weights (fp32) ----------------
__global__ __launch_bounds__(256) void k_fold(const float* __restrict__ fw1,
    const float* __restrict__ fw2, const float* __restrict__ w1m,
    float* __restrict__ w1f, float* __restrict__ w2f){
  int id = blockIdx.x*256 + threadIdx.x;      // 0..262143
  int half = id >> 17;
  int r = id & 131071;
  int i  = r >> 15;
  int in = (r >> 10) & 31;
  int k  = (r >> 5) & 31;
  int o  = r & 31;
  const float* src = half ? fw2 : fw1;
  const float* wm  = w1m + i*1024 + o*32;
  const float* sp  = src + ((size_t)((i*32+in)*1024 + k))*2;
  float sR = 0.f, sI = 0.f;
  #pragma unroll
  for (int c=0;c<32;c++){
    float w = wm[c];
    sR += w * sp[c*64];
    sI += w * sp[c*64+1];
  }
  float* dst = half ? w2f : w1f;
  size_t oi = ((size_t)((i*32+in)*32 + k)*32 + o)*2;
  dst[oi] = sR; dst[oi+1] = sI;
}

// ---------------- fc0 -> h (fp32) ----------------
__global__ __launch_bounds__(256) void k_fc0(const float* __restrict__ x,
    const float* __restrict__ gx, const float* __restrict__ gy,
    const float* __restrict__ fw, const float* __restrict__ fb,
    float* __restrict__ h){
  int p = blockIdx.x*256 + threadIdx.x;
  if (p >= NPTS) return;
  int b = p/NPIX, r = p%NPIX, m = r/NSX, n = r%NSX;
  const float* xp = x + (size_t)p*NCIN;
  float xv[NCIN+2];
  #pragma unroll
  for (int j=0;j<NCIN;j++) xv[j] = xp[j];
  xv[16] = gx[n]; xv[17] = gy[m];
  float acc[NW];
  #pragma unroll
  for (int o=0;o<NW;o++) acc[o] = fb[o];
  #pragma unroll
  for (int j=0;j<NCIN+2;j++){
    float v = xv[j];
    #pragma unroll
    for (int o=0;o<NW;o++) acc[o] += v*fw[j*32+o];
  }
  float* hp = h + (size_t)b*NW*NPIX + r;
  #pragma unroll
  for (int o=0;o<NW;o++) hp[(size_t)o*NPIX] = acc[o];
}

// ---------------- MFMA forward DFT over y: fty[bb][c][k][n] = pack(Re,Im) ----------------
__global__ __launch_bounds__(256) void k_fwdy(const float* __restrict__ h,
    const ushort* __restrict__ Abfy, uint* __restrict__ fty, int b0){
  __shared__ uint Bt[64*18];
  int bx = blockIdx.x;
  int nt6 = bx % 6; int c = (bx/6) & 31; int bb = bx/192;
  int n0 = nt6*64;
  int tid = threadIdx.x;
  int l = tid & 63, g = tid >> 6;
  int c15 = l & 15, q = l >> 4;
  const float* hb = h + (size_t)((b0+bb)*NW + c)*NPIX;
  bf16x8 afr[6];
  #pragma unroll
  for (int ks=0; ks<6; ks++)
    afr[ks] = *(const bf16x8*)(Abfy + (size_t)(16*g + c15)*192 + ks*32 + q*8);
  f32x4 acc[4];
  #pragma unroll
  for (int t=0;t<4;t++) acc[t] = (f32x4){0.f,0.f,0.f,0.f};
  int n = n0 + l;
  bool nv = n < NSX;
  for (int ks=0; ks<6; ks++){
    __syncthreads();
    float v[8];
    #pragma unroll
    for (int j=0;j<8;j++){
      int m = ks*32 + 8*g + j;
      v[j] = (nv && m < NSY) ? hb[(size_t)m*NSX + n] : 0.f;
    }
    #pragma unroll
    for (int i=0;i<4;i++)
      Bt[l*18 + 4*g + i] = packbf2(v[2*i], v[2*i+1]);
    __syncthreads();
    #pragma unroll
    for (int nt=0; nt<4; nt++){
      const uint* bp = &Bt[(nt*16 + c15)*18 + q*4];
      U4 bu;
      uint2 lo = *(const uint2*)(bp);
      uint2 hi = *(const uint2*)(bp+2);
      bu.u[0]=lo.x; bu.u[1]=lo.y; bu.u[2]=hi.x; bu.u[3]=hi.y;
      acc[nt] = __builtin_amdgcn_mfma_f32_16x16x32_bf16(afr[ks], bu.v, acc[nt], 0,0,0);
    }
  }
  uint* fb = fty + (size_t)(bb*NW + c)*32*NSX;
  int k0 = 8*g + 2*q;
  #pragma unroll
  for (int nt=0; nt<4; nt++){
    int nn = n0 + nt*16 + c15;
    if (nn < NSX){
      fb[(size_t)k0*NSX + nn]     = packbf2(acc[nt][0], acc[nt][1]);
      fb[(size_t)(k0+1)*NSX + nn] = packbf2(acc[nt][2], acc[nt][3]);
    }
  }
}

// ---------------- MFMA forward DFT over x: ftx[bb][c][k][m] ----------------
__global__ __launch_bounds__(256) void k_fwdx(const float* __restrict__ h,
    const ushort* __restrict__ Abfx, uint* __restrict__ ftx, int b0){
  __shared__ uint Bt[64*18];
  int bx = blockIdx.x;
  int mt = bx % 3; int c = (bx/3) & 31; int bb = bx/96;
  int m0 = mt*64;
  int tid = threadIdx.x;
  int l = tid & 63, g = tid >> 6;
  int c15 = l & 15, q = l >> 4;
  const float* hb = h + (size_t)((b0+bb)*NW + c)*NPIX;
  bf16x8 afr[12];
  #pragma unroll
  for (int ks=0; ks<12; ks++)
    afr[ks] = *(const bf16x8*)(Abfx + (size_t)(16*g + c15)*384 + ks*32 + q*8);
  f32x4 acc[4];
  #pragma unroll
  for (int t=0;t<4;t++) acc[t] = (f32x4){0.f,0.f,0.f,0.f};
  int m = m0 + l;
  bool mv = m < NSY;
  for (int ks=0; ks<12; ks++){
    __syncthreads();
    int nb = ks*32 + 8*g;
    float4 p0 = {0.f,0.f,0.f,0.f}, p1 = {0.f,0.f,0.f,0.f};
    if (mv && nb < NSX){
      p0 = *(const float4*)(hb + (size_t)m*NSX + nb);
      p1 = *(const float4*)(hb + (size_t)m*NSX + nb + 4);
    }
    Bt[l*18 + 4*g + 0] = packbf2(p0.x, p0.y);
    Bt[l*18 + 4*g + 1] = packbf2(p0.z, p0.w);
    Bt[l*18 + 4*g + 2] = packbf2(p1.x, p1.y);
    Bt[l*18 + 4*g + 3] = packbf2(p1.z, p1.w);
    __syncthreads();
    #pragma unroll
    for (int nt=0; nt<4; nt++){
      const uint* bp = &Bt[(nt*16 + c15)*18 + q*4];
      U4 bu;
      uint2 lo = *(const uint2*)(bp);
      uint2 hi = *(const uint2*)(bp+2);
      bu.u[0]=lo.x; bu.u[1]=lo.y; bu.u[2]=hi.x; bu.u[3]=hi.y;
      acc[nt] = __builtin_amdgcn_mfma_f32_16x16x32_bf16(afr[ks], bu.v, acc[nt], 0,0,0);
    }
  }
  uint* fb = ftx + (size_t)(bb*NW + c)*32*NSY;
  int k0 = 8*g + 2*q;
  #pragma unroll
  for (int nt=0; nt<4; nt++){
    int mm = m0 + nt*16 + c15;
    if (mm < NSY){
      fb[(size_t)k0*NSY + mm]     = packbf2(acc[nt][0], acc[nt][1]);
      fb[(size_t)(k0+1)*NSY + mm] = packbf2(acc[nt][2], acc[nt][3]);
    }
  }
}

// ---------------- unified per-mode complex channel mix (y + x in one dispatch) ----------------
// oo[bb][o][k][n] = sum_in ft[bb][in][k][n] * wf[in][k][o]   (packed Re|Im dwords)
__global__ __launch_bounds__(192) void k_mix(const uint* __restrict__ fty,
    const uint* __restrict__ ftx, const float* __restrict__ w1f,
    const float* __restrict__ w2f, uint* __restrict__ oy, uint* __restrict__ ox,
    int ylim){
  int bx = blockIdx.x;
  const uint* ft; const float* wf; uint* oo; int Nlen, k, bb, n;
  if (bx < ylim){
    int t = bx; int nt = t & 1; k = (t>>1) & 31; bb = t >> 6;
    n = nt*192 + threadIdx.x; ft = fty; wf = w1f; oo = oy; Nlen = NSX;
  } else {
    int t = bx - ylim; k = t & 31; bb = t >> 5;
    n = threadIdx.x; ft = ftx; wf = w2f; oo = ox; Nlen = NSY;
  }
  bool valid = n < Nlen;
  int nn = valid ? n : (Nlen-1);
  const uint* fb = ft + ((size_t)(bb*NW)*32 + k)*Nlen + nn;
  const float* wb = wf + (size_t)k*64;
  float aR[32], aI[32];
  #pragma unroll
  for (int o=0;o<32;o++){ aR[o]=0.f; aI[o]=0.f; }
  for (int in=0; in<32; in++){
    uint f = fb[(size_t)in*32*Nlen];
    float fR = bf2f((ushort)(f & 0xffffu));
    float fI = bf2f((ushort)(f >> 16));
    const float* wrow = wb + in*2048;
    #pragma unroll
    for (int o=0;o<32;o++){
      float wR = wrow[o*2], wI = wrow[o*2+1];
      aR[o] += fR*wR - fI*wI;
      aI[o] += fR*wI + fI*wR;
    }
  }
  if (valid){
    uint* ob = oo + ((size_t)(bb*NW)*32 + k)*Nlen + n;
    #pragma unroll
    for (int o=0;o<32;o++){
      ob[(size_t)o*32*Nlen] = packbf2(aR[o], aI[o]);
    }
  }
}

// ---------------- MFMA inverse (y+x combined) -> x2bf[bb][o][m][n] (bf16, +b1) ----------------
__global__ __launch_bounds__(256) void k_inv(const uint* __restrict__ oyb,
    const uint* __restrict__ oxb, const ushort* __restrict__ VyCT,
    const ushort* __restrict__ VxCT, const float* __restrict__ b1,
    ushort* __restrict__ x2bf){
  __shared__ uint At[64*34];     // [m_local][k 0..31]
  __shared__ uint Bt[64*34];     // [n_local][k 0..31]
  int bx = blockIdx.x;
  int nt6 = bx % 6; int mt = (bx/6) % 3; int o = (bx/18) & 31; int bb = bx/576;
  int m0 = mt*64, n0 = nt6*64;
  int tid = threadIdx.x;
  int l = tid & 63, g = tid >> 6;
  int c15 = l & 15, q = l >> 4;
  const uint* oxp = oxb + (size_t)(bb*NW + o)*32*NSY;
  const uint* oyp = oyb + (size_t)(bb*NW + o)*32*NSX;
  {
    int m = m0 + l; bool mv = m < NSY;
    #pragma unroll
    for (int i=0;i<8;i++){
      int kp = 8*g + i;
      At[l*34 + kp] = mv ? oxp[(size_t)kp*NSY + m] : 0u;
    }
    int n = n0 + l; bool nvv = n < NSX;
    #pragma unroll
    for (int i=0;i<8;i++){
      int kp = 8*g + i;
      Bt[l*34 + kp] = nvv ? oyp[(size_t)kp*NSX + n] : 0u;
    }
  }
  __syncthreads();
  bf16x8 afr[4];
  afr[0] = *(const bf16x8*)(VyCT + (size_t)(m0 + 16*g + c15)*64 + q*8);
  afr[1] = *(const bf16x8*)(VyCT + (size_t)(m0 + 16*g + c15)*64 + 32 + q*8);
  {
    const uint* ap = &At[(16*g + c15)*34 + q*4];
    U4 au; uint2 lo = *(const uint2*)ap; uint2 hi = *(const uint2*)(ap+2);
    au.u[0]=lo.x; au.u[1]=lo.y; au.u[2]=hi.x; au.u[3]=hi.y;
    afr[2] = au.v;
    const uint* ap2 = &At[(16*g + c15)*34 + 16 + q*4];
    U4 au2; uint2 lo2 = *(const uint2*)ap2; uint2 hi2 = *(const uint2*)(ap2+2);
    au2.u[0]=lo2.x; au2.u[1]=lo2.y; au2.u[2]=hi2.x; au2.u[3]=hi2.y;
    afr[3] = au2.v;
  }
  f32x4 acc[4];
  #pragma unroll
  for (int t=0;t<4;t++) acc[t] = (f32x4){0.f,0.f,0.f,0.f};
  #pragma unroll
  for (int nt=0; nt<4; nt++){
    int nb = n0 + nt*16 + c15;
    const uint* bp = &Bt[(nt*16 + c15)*34 + q*4];
    U4 b0u; { uint2 lo = *(const uint2*)bp; uint2 hi = *(const uint2*)(bp+2);
      b0u.u[0]=lo.x; b0u.u[1]=lo.y; b0u.u[2]=hi.x; b0u.u[3]=hi.y; }
    const uint* bp1 = &Bt[(nt*16 + c15)*34 + 16 + q*4];
    U4 b1u; { uint2 lo = *(const uint2*)bp1; uint2 hi = *(const uint2*)(bp1+2);
      b1u.u[0]=lo.x; b1u.u[1]=lo.y; b1u.u[2]=hi.x; b1u.u[3]=hi.y; }
    bf16x8 b2f = *(const bf16x8*)(VxCT + (size_t)nb*64 + q*8);
    bf16x8 b3f = *(const bf16x8*)(VxCT + (size_t)nb*64 + 32 + q*8);
    acc[nt] = __builtin_amdgcn_mfma_f32_16x16x32_bf16(afr[0], b0u.v, acc[nt], 0,0,0);
    acc[nt] = __builtin_amdgcn_mfma_f32_16x16x32_bf16(afr[1], b1u.v, acc[nt], 0,0,0);
    acc[nt] = __builtin_amdgcn_mfma_f32_16x16x32_bf16(afr[2], b2f, acc[nt], 0,0,0);
    acc[nt] = __builtin_amdgcn_mfma_f32_16x16x32_bf16(afr[3], b3f, acc[nt], 0,0,0);
  }
  float bias = b1[o];
  ushort* xp = x2bf + (size_t)(bb*NW + o)*NPIX;
  #pragma unroll
  for (int nt=0; nt<4; nt++){
    int n = n0 + nt*16 + c15;
    if (n < NSX){
      #pragma unroll
      for (int r=0;r<4;r++){
        int m = m0 + 16*g + q*4 + r;
        if (m < NSY) xp[(size_t)m*NSX + n] = f2bf(acc[nt][r] + bias);
      }
    }
  }
}

// ---------------- pointwise: h += (gelu?)(W2 @ gelu(x2) + b2) ----------------
__global__ __launch_bounds__(256) void k_pw(const ushort* __restrict__ x2bf,
    const float* __restrict__ w2m, const float* __restrict__ b2,
    float* __restrict__ h, int last, int b0, int nloc){
  int p = blockIdx.x*256 + threadIdx.x;
  if (p >= nloc*NPIX) return;
  int bb = p/NPIX, r = p%NPIX;
  const ushort* xb = x2bf + (size_t)bb*NW*NPIX + r;
  float t[NW];
  #pragma unroll
  for (int c=0;c<NW;c++) t[c] = gelu_f(bf2f(xb[(size_t)c*NPIX]));
  float* hb = h + (size_t)(b0+bb)*NW*NPIX + r;
  for (int o=0;o<NW;o++){
    float a = b2[o];
    #pragma unroll
    for (int c=0;c<NW;c++) a += t[c]*w2m[o*32+c];
    hb[(size_t)o*NPIX] += last ? a : gelu_f(a);
  }
}

// ---------------- MFMA fc1 + gelu + fc2 (reads fp32 h planar) ----------------
__global__ __launch_bounds__(256) void k_fc12m(const float* __restrict__ h,
    const ushort* __restrict__ f1Tbf, const float* __restrict__ f1b,
    const float* __restrict__ f2w, const float* __restrict__ f2b,
    float* __restrict__ out){
  int blk = blockIdx.x; int tid = threadIdx.x;
  int g = tid >> 6, lane = tid & 63;
  int c15 = lane & 15, q = lane >> 4;
  int pbase = blk*64 + g*16;
  int pglob = pbase + c15;
  int b = pglob/NPIX, r = pglob%NPIX;
  const float* hb = h + (size_t)b*NW*NPIX + r;
  U4 au;
  #pragma unroll
  for (int i=0;i<4;i++){
    float v0 = hb[(size_t)(q*8 + 2*i)*NPIX];
    float v1 = hb[(size_t)(q*8 + 2*i + 1)*NPIX];
    au.u[i] = packbf2(v0, v1);
  }
  bf16x8 afr = au.v;
  f32x4 acc[8];
  #pragma unroll
  for (int t=0;t<8;t++) acc[t] = (f32x4){0.f,0.f,0.f,0.f};
  #pragma unroll
  for (int nt=0; nt<8; nt++){
    bf16x8 bfr = *(const bf16x8*)(f1Tbf + (size_t)(nt*16 + c15)*32 + q*8);
    acc[nt] = __builtin_amdgcn_mfma_f32_16x16x32_bf16(afr, bfr, acc[nt], 0,0,0);
  }
  float s[4] = {0.f,0.f,0.f,0.f};
  #pragma unroll
  for (int nt=0; nt<8; nt++){
    int j = nt*16 + c15;
    float bj = f1b[j], wj = f2w[j];
    #pragma unroll
    for (int r2=0;r2<4;r2++) s[r2] += gelu_f(acc[nt][r2] + bj) * wj;
  }
  #pragma unroll
  for (int msk=1; msk<16; msk<<=1){
    #pragma unroll
    for (int r2=0;r2<4;r2++) s[r2] += __shfl_xor(s[r2], msk, 64);
  }
  if (c15 == 0){
    float fb2 = f2b[0];
    float4 v = {s[0]+fb2, s[1]+fb2, s[2]+fb2, s[3]+fb2};
    *(float4*)(out + pbase + q*4) = v;
  }
}

extern "C" void kernel_launch(void* const* d_in, const int* in_sizes, int n_in,
                              void* d_out, int out_size, void* d_ws, size_t ws_size,
                              hipStream_t stream) {
  const float* x     = (const float*)d_in[0];
  const float* sx    = (const float*)d_in[1];
  const float* sy    = (const float*)d_in[2];
  const float* fc0_w = (const float*)d_in[3];
  const float* fc0_b = (const float*)d_in[4];
  const float* fw1   = (const float*)d_in[5];
  const float* fw2   = (const float*)d_in[6];
  const float* w1m   = (const float*)d_in[7];
  const float* b1    = (const float*)d_in[8];
  const float* w2m   = (const float*)d_in[9];
  const float* b2    = (const float*)d_in[10];
  const float* fc1_w = (const float*)d_in[11];
  const float* fc1_b = (const float*)d_in[12];
  const float* fc2_w = (const float*)d_in[13];
  const float* fc2_b = (const float*)d_in[14];
  float* out = (float*)d_out;

  char* wsb = (char*)d_ws;
  size_t off = 0;
  auto alloc = [&](size_t bytes)->char*{
    char* p = wsb + off;
    off = (off + bytes + 255) & ~(size_t)255;
    return p;
  };
  float*  h     = (float*)alloc((size_t)NB*NW*NPIX*4);     // 132.7 MB
  ushort* Abfy  = (ushort*)alloc(64*192*2);
  ushort* Abfx  = (ushort*)alloc(64*384*2);
  ushort* VyCT  = (ushort*)alloc(192*64*2);
  ushort* VxCT  = (ushort*)alloc(384*64*2);
  ushort* f1Tbf = (ushort*)alloc(128*32*2);
  float*  gx    = (float*)alloc(NSX*4);
  float*  gy    = (float*)alloc(NSY*4);
  float*  w1f   = (float*)alloc(262144*4);
  float*  w2f   = (float*)alloc(262144*4);
  const size_t fixedB = off;

  // per-batch regions: x2bf (bf16, 4,147,200 B) ALIASES [fty | ftx | extra]
  // (fty/ftx dead after k_mix, x2 born at k_inv; 1,474,560+737,280+1,935,360 = 4,147,200)
  const size_t szX2  = (size_t)NW*NPIX*2;
  const size_t szFty = (size_t)NW*32*NSX*4;
  const size_t szFtx = (size_t)NW*32*NSY*4;
  const size_t szOy  = szFty, szOx = szFtx;
  const size_t perB  = szX2 + szOy + szOx;      // 6,359,040 B

  int NC = 16;
  while (NC > 1 && fixedB + (size_t)NC*perB + 4096 > ws_size) NC >>= 1;
  char* pb = wsb + fixedB;
  ushort* x2bf = (ushort*)pb;
  uint*   fty  = (uint*)pb;                               // aliases x2bf head
  uint*   ftx  = (uint*)(pb + (size_t)NC*szFty);          // aliases x2bf tail
  uint*   oy   = (uint*)(pb + (size_t)NC*szX2);
  uint*   ox   = (uint*)((char*)oy + (size_t)NC*szOy);

  k_prep<<<96, 256, 0, stream>>>(sx, sy, fc1_w, Abfy, Abfx, VyCT, VxCT, f1Tbf, gx, gy);
  k_fold<<<1024, 256, 0, stream>>>(fw1, fw2, w1m, w1f, w2f);
  k_fc0<<<4050, 256, 0, stream>>>(x, gx, gy, fc0_w, fc0_b, h);

  for (int i=0;i<4;i++){
    for (int b0=0; b0<NB; b0+=NC){
      k_fwdy<<<NC*192, 256, 0, stream>>>(h, Abfy, fty, b0);
      k_fwdx<<<NC*96, 256, 0, stream>>>(h, Abfx, ftx, b0);
      k_mix<<<NC*96, 192, 0, stream>>>(fty, ftx, w1f + (size_t)i*65536,
                                       w2f + (size_t)i*65536, oy, ox, NC*64);
      k_inv<<<NC*576, 256, 0, stream>>>(oy, ox, VyCT, VxCT, b1 + i*32, x2bf);
      k_pw<<<(NC*NPIX + 255)/256, 256, 0, stream>>>(x2bf, w2m + (size_t)i*1024,
                                                    b2 + i*32, h, (int)(i==3), b0, NC);
    }
  }

  k_fc12m<<<NPTS/64, 256, 0, stream>>>(h, f1Tbf, fc1_b, fc2_w, fc2_b, out);
}

// Round 8
// 1216.445 us; speedup vs baseline: 23.9298x; 1.0561x over previous
//
#include <hip/hip_runtime.h>
#include <math.h>

#define NB 16
#define NSY 180
#define NSX 360
#define NCIN 16
#define NW 32
#define NMODES 32
#define NPIX (NSY*NSX)     // 64800
#define NPTS (NB*NPIX)     // 1036800

typedef unsigned int uint;
typedef unsigned short ushort;
typedef __attribute__((ext_vector_type(8))) short bf16x8;
typedef __attribute__((ext_vector_type(4))) float f32x4;

union U4 { uint u[4]; bf16x8 v; };

// tanh-gelu with fast rcp: v*sigmoid(1.5957691*(v+0.044715 v^3))
__device__ __forceinline__ float gelu_f(float v){
  float u = v*(-1.5957691216f - 0.0713548163f*v*v);
  return v * __builtin_amdgcn_rcpf(1.f + __expf(u));
}
__device__ __forceinline__ ushort f2bf(float x){
  uint u = __float_as_uint(x);
  return (ushort)((u + 0x7FFFu + ((u>>16)&1u)) >> 16);
}
__device__ __forceinline__ uint packbf2(float a, float b){
  return (uint)f2bf(a) | ((uint)f2bf(b) << 16);
}
__device__ __forceinline__ float bf2f(ushort u){
  return __uint_as_float(((uint)u) << 16);
}

// ---------------- prep: bf16 Vandermonde (zero-padded), grid, fc1^T ----------------
__global__ __launch_bounds__(256) void k_prep(const float* __restrict__ sx,
    const float* __restrict__ sy, const float* __restrict__ fc1_w,
    ushort* __restrict__ Abfy, ushort* __restrict__ Abfx,
    ushort* __restrict__ VyCT, ushort* __restrict__ VxCT,
    ushort* __restrict__ f1Tbf, float* __restrict__ gx, float* __restrict__ gy){
  int idx = blockIdx.x*256 + threadIdx.x;
  float sx0 = sx[0], sxL = sx[NSX-1];
  float sy0 = sy[0], syL = sy[NSY-1];
  const float scy = 0.07453559924999298980f;   // 1/sqrt(180)
  const float scx = 0.05270462766947298886f;   // 1/sqrt(360)
  if (idx < NSX) gx[idx] = (sx[idx]-sx0)/sxL;
  if (idx < NSY) gy[idx] = (sy[idx]-sy0)/syL;
  if (idx < 64*192){
    int kri = idx/192, m = idx%192;
    float val = 0.f;
    if (m < NSY){
      int k = kri>>1;
      float p = (sy[m]-sy0)/(syL-sy0);
      float ang = -6.2831853071795864769f*(float)k*p;
      val = ((kri&1)? sinf(ang) : cosf(ang))*scy;
    }
    Abfy[idx] = f2bf(val);
  }
  if (idx < 192*64){
    int m = idx/64, kri = idx%64;
    float val = 0.f;
    if (m < NSY){
      int k = kri>>1;
      float p = (sy[m]-sy0)/(syL-sy0);
      float ang = -6.2831853071795864769f*(float)k*p;
      val = ((kri&1)? sinf(ang) : cosf(ang))*scy;
    }
    VyCT[idx] = f2bf(val);
  }
  if (idx < 64*384){
    int kri = idx/384, n = idx%384;
    float val = 0.f;
    if (n < NSX){
      int k = kri>>1;
      float p = (sx[n]-sx0)/(sxL-sx0);
      float ang = -6.2831853071795864769f*(float)k*p;
      val = ((kri&1)? sinf(ang) : cosf(ang))*scx;
    }
    Abfx[idx] = f2bf(val);
  }
  if (idx < 384*64){
    int n = idx/64, kri = idx%64;
    float val = 0.f;
    if (n < NSX){
      int k = kri>>1;
      float p = (sx[n]-sx0)/(sxL-sx0);
      float ang = -6.2831853071795864769f*(float)k*p;
      val = ((kri&1)? sinf(ang) : cosf(ang))*scx;
    }
    VxCT[idx] = f2bf(val);
  }
  if (idx < 128*32){
    int j = idx >> 5, c = idx & 31;
    f1Tbf[idx] = f2bf(fc1_w[c*128 + j]);
  }
}

// ---------------- fold pointwise w1 into the mode-mix weights (fp32) ----------------
__global__ __launch_bounds__(256) void k_fold(const float* __restrict__ fw1,
    const float* __restrict__ fw2, const float* __restrict__ w1m,
    float* __restrict__ w1f, float* __restrict__ w2f){
  int id = blockIdx.x*256 + threadIdx.x;      // 0..262143
  int half = id >> 17;
  int r = id & 131071;
  int i  = r >> 15;
  int in = (r >> 10) & 31;
  int k  = (r >> 5) & 31;
  int o  = r & 31;
  const float* src = half ? fw2 : fw1;
  const float* wm  = w1m + i*1024 + o*32;
  const float* sp  = src + ((size_t)((i*32+in)*1024 + k))*2;
  float sR = 0.f, sI = 0.f;
  #pragma unroll
  for (int c=0;c<32;c++){
    float w = wm[c];
    sR += w * sp[c*64];
    sI += w * sp[c*64+1];
  }
  float* dst = half ? w2f : w1f;
  size_t oi = ((size_t)((i*32+in)*32 + k)*32 + o)*2;
  dst[oi] = sR; dst[oi+1] = sI;
}

// ---------------- fc0 -> hbf (bf16 residual stream) ----------------
__global__ __launch_bounds__(256) void k_fc0(const float* __restrict__ x,
    const float* __restrict__ gx, const float* __restrict__ gy,
    const float* __restrict__ fw, const float* __restrict__ fb,
    ushort* __restrict__ hbf){
  int p = blockIdx.x*256 + threadIdx.x;
  if (p >= NPTS) return;
  int b = p/NPIX, r = p%NPIX, m = r/NSX, n = r%NSX;
  const float* xp = x + (size_t)p*NCIN;
  float xv[NCIN+2];
  #pragma unroll
  for (int j=0;j<NCIN;j++) xv[j] = xp[j];
  xv[16] = gx[n]; xv[17] = gy[m];
  float acc[NW];
  #pragma unroll
  for (int o=0;o<NW;o++) acc[o] = fb[o];
  #pragma unroll
  for (int j=0;j<NCIN+2;j++){
    float v = xv[j];
    #pragma unroll
    for (int o=0;o<NW;o++) acc[o] += v*fw[j*32+o];
  }
  ushort* hq = hbf + (size_t)b*NW*NPIX + r;
  #pragma unroll
  for (int o=0;o<NW;o++) hq[(size_t)o*NPIX] = f2bf(acc[o]);
}

// ---------------- merged MFMA forward DFTs (y + x in one dispatch) ----------------
// y-part: fty[bb][c][k][n] = pack(Re,Im) of sum_m hbf[..][m][n]*Vy[k][m]
// x-part: ftx[bb][c][k][m] = pack(Re,Im) of sum_n hbf[..][m][n]*Vx[k][n]
__global__ __launch_bounds__(256) void k_fwd(const ushort* __restrict__ hbf,
    const ushort* __restrict__ Abfy, const ushort* __restrict__ Abfx,
    uint* __restrict__ fty, uint* __restrict__ ftx, int b0, int ylim){
  __shared__ uint Bt[64*18];
  int bx = blockIdx.x;
  int tid = threadIdx.x;
  int l = tid & 63, g = tid >> 6;
  int c15 = l & 15, q = l >> 4;
  if (bx < ylim){
    int nt6 = bx % 6; int c = (bx/6) & 31; int bb = bx/192;
    int n0 = nt6*64;
    const ushort* hb = hbf + (size_t)((b0+bb)*NW + c)*NPIX;
    bf16x8 afr[6];
    #pragma unroll
    for (int ks=0; ks<6; ks++)
      afr[ks] = *(const bf16x8*)(Abfy + (size_t)(16*g + c15)*192 + ks*32 + q*8);
    f32x4 acc[4];
    #pragma unroll
    for (int t=0;t<4;t++) acc[t] = (f32x4){0.f,0.f,0.f,0.f};
    int n = n0 + l;
    bool nv = n < NSX;
    for (int ks=0; ks<6; ks++){
      __syncthreads();
      ushort v[8];
      #pragma unroll
      for (int j=0;j<8;j++){
        int m = ks*32 + 8*g + j;
        v[j] = (nv && m < NSY) ? hb[(size_t)m*NSX + n] : (ushort)0;
      }
      #pragma unroll
      for (int i=0;i<4;i++)
        Bt[l*18 + 4*g + i] = (uint)v[2*i] | ((uint)v[2*i+1] << 16);
      __syncthreads();
      #pragma unroll
      for (int nt=0; nt<4; nt++){
        const uint* bp = &Bt[(nt*16 + c15)*18 + q*4];
        U4 bu;
        uint2 lo = *(const uint2*)(bp);
        uint2 hi = *(const uint2*)(bp+2);
        bu.u[0]=lo.x; bu.u[1]=lo.y; bu.u[2]=hi.x; bu.u[3]=hi.y;
        acc[nt] = __builtin_amdgcn_mfma_f32_16x16x32_bf16(afr[ks], bu.v, acc[nt], 0,0,0);
      }
    }
    uint* fb = fty + (size_t)(bb*NW + c)*32*NSX;
    int k0 = 8*g + 2*q;
    #pragma unroll
    for (int nt=0; nt<4; nt++){
      int nn = n0 + nt*16 + c15;
      if (nn < NSX){
        fb[(size_t)k0*NSX + nn]     = packbf2(acc[nt][0], acc[nt][1]);
        fb[(size_t)(k0+1)*NSX + nn] = packbf2(acc[nt][2], acc[nt][3]);
      }
    }
  } else {
    int t = bx - ylim;
    int mt = t % 3; int c = (t/3) & 31; int bb = t/96;
    int m0 = mt*64;
    const ushort* hb = hbf + (size_t)((b0+bb)*NW + c)*NPIX;
    bf16x8 afr[12];
    #pragma unroll
    for (int ks=0; ks<12; ks++)
      afr[ks] = *(const bf16x8*)(Abfx + (size_t)(16*g + c15)*384 + ks*32 + q*8);
    f32x4 acc[4];
    #pragma unroll
    for (int tt=0;tt<4;tt++) acc[tt] = (f32x4){0.f,0.f,0.f,0.f};
    int m = m0 + l;
    bool mv = m < NSY;
    for (int ks=0; ks<12; ks++){
      __syncthreads();
      int nb = ks*32 + 8*g;
      uint4 p = {0u,0u,0u,0u};
      if (mv && nb < NSX) p = *(const uint4*)(hb + (size_t)m*NSX + nb);
      Bt[l*18 + 4*g + 0] = p.x;
      Bt[l*18 + 4*g + 1] = p.y;
      Bt[l*18 + 4*g + 2] = p.z;
      Bt[l*18 + 4*g + 3] = p.w;
      __syncthreads();
      #pragma unroll
      for (int nt=0; nt<4; nt++){
        const uint* bp = &Bt[(nt*16 + c15)*18 + q*4];
        U4 bu;
        uint2 lo = *(const uint2*)(bp);
        uint2 hi = *(const uint2*)(bp+2);
        bu.u[0]=lo.x; bu.u[1]=lo.y; bu.u[2]=hi.x; bu.u[3]=hi.y;
        acc[nt] = __builtin_amdgcn_mfma_f32_16x16x32_bf16(afr[ks], bu.v, acc[nt], 0,0,0);
      }
    }
    uint* fb = ftx + (size_t)(bb*NW + c)*32*NSY;
    int k0 = 8*g + 2*q;
    #pragma unroll
    for (int nt=0; nt<4; nt++){
      int mm = m0 + nt*16 + c15;
      if (mm < NSY){
        fb[(size_t)k0*NSY + mm]     = packbf2(acc[nt][0], acc[nt][1]);
        fb[(size_t)(k0+1)*NSY + mm] = packbf2(acc[nt][2], acc[nt][3]);
      }
    }
  }
}

// ---------------- unified per-mode complex channel mix (y + x in one dispatch) ----------------
__global__ __launch_bounds__(192) void k_mix(const uint* __restrict__ fty,
    const uint* __restrict__ ftx, const float* __restrict__ w1f,
    const float* __restrict__ w2f, uint* __restrict__ oy, uint* __restrict__ ox,
    int ylim){
  int bx = blockIdx.x;
  const uint* ft; const float* wf; uint* oo; int Nlen, k, bb, n;
  if (bx < ylim){
    int t = bx; int nt = t & 1; k = (t>>1) & 31; bb = t >> 6;
    n = nt*192 + threadIdx.x; ft = fty; wf = w1f; oo = oy; Nlen = NSX;
  } else {
    int t = bx - ylim; k = t & 31; bb = t >> 5;
    n = threadIdx.x; ft = ftx; wf = w2f; oo = ox; Nlen = NSY;
  }
  bool valid = n < Nlen;
  int nn = valid ? n : (Nlen-1);
  const uint* fb = ft + ((size_t)(bb*NW)*32 + k)*Nlen + nn;
  const float* wb = wf + (size_t)k*64;
  float aR[32], aI[32];
  #pragma unroll
  for (int o=0;o<32;o++){ aR[o]=0.f; aI[o]=0.f; }
  for (int in=0; in<32; in++){
    uint f = fb[(size_t)in*32*Nlen];
    float fR = bf2f((ushort)(f & 0xffffu));
    float fI = bf2f((ushort)(f >> 16));
    const float* wrow = wb + in*2048;
    #pragma unroll
    for (int o=0;o<32;o++){
      float wR = wrow[o*2], wI = wrow[o*2+1];
      aR[o] += fR*wR - fI*wI;
      aI[o] += fR*wI + fI*wR;
    }
  }
  if (valid){
    uint* ob = oo + ((size_t)(bb*NW)*32 + k)*Nlen + n;
    #pragma unroll
    for (int o=0;o<32;o++){
      ob[(size_t)o*32*Nlen] = packbf2(aR[o], aI[o]);
    }
  }
}

// ---------------- MFMA inverse (y+x combined) -> x2bf[bb][o][m][n] (bf16, +b1) ----------------
__global__ __launch_bounds__(256) void k_inv(const uint* __restrict__ oyb,
    const uint* __restrict__ oxb, const ushort* __restrict__ VyCT,
    const ushort* __restrict__ VxCT, const float* __restrict__ b1,
    ushort* __restrict__ x2bf){
  __shared__ uint At[64*34];     // [m_local][k 0..31]
  __shared__ uint Bt[64*34];     // [n_local][k 0..31]
  int bx = blockIdx.x;
  int nt6 = bx % 6; int mt = (bx/6) % 3; int o = (bx/18) & 31; int bb = bx/576;
  int m0 = mt*64, n0 = nt6*64;
  int tid = threadIdx.x;
  int l = tid & 63, g = tid >> 6;
  int c15 = l & 15, q = l >> 4;
  const uint* oxp = oxb + (size_t)(bb*NW + o)*32*NSY;
  const uint* oyp = oyb + (size_t)(bb*NW + o)*32*NSX;
  {
    int m = m0 + l; bool mv = m < NSY;
    #pragma unroll
    for (int i=0;i<8;i++){
      int kp = 8*g + i;
      At[l*34 + kp] = mv ? oxp[(size_t)kp*NSY + m] : 0u;
    }
    int n = n0 + l; bool nvv = n < NSX;
    #pragma unroll
    for (int i=0;i<8;i++){
      int kp = 8*g + i;
      Bt[l*34 + kp] = nvv ? oyp[(size_t)kp*NSX + n] : 0u;
    }
  }
  __syncthreads();
  bf16x8 afr[4];
  afr[0] = *(const bf16x8*)(VyCT + (size_t)(m0 + 16*g + c15)*64 + q*8);
  afr[1] = *(const bf16x8*)(VyCT + (size_t)(m0 + 16*g + c15)*64 + 32 + q*8);
  {
    const uint* ap = &At[(16*g + c15)*34 + q*4];
    U4 au; uint2 lo = *(const uint2*)ap; uint2 hi = *(const uint2*)(ap+2);
    au.u[0]=lo.x; au.u[1]=lo.y; au.u[2]=hi.x; au.u[3]=hi.y;
    afr[2] = au.v;
    const uint* ap2 = &At[(16*g + c15)*34 + 16 + q*4];
    U4 au2; uint2 lo2 = *(const uint2*)ap2; uint2 hi2 = *(const uint2*)(ap2+2);
    au2.u[0]=lo2.x; au2.u[1]=lo2.y; au2.u[2]=hi2.x; au2.u[3]=hi2.y;
    afr[3] = au2.v;
  }
  f32x4 acc[4];
  #pragma unroll
  for (int t=0;t<4;t++) acc[t] = (f32x4){0.f,0.f,0.f,0.f};
  #pragma unroll
  for (int nt=0; nt<4; nt++){
    int nb = n0 + nt*16 + c15;
    const uint* bp = &Bt[(nt*16 + c15)*34 + q*4];
    U4 b0u; { uint2 lo = *(const uint2*)bp; uint2 hi = *(const uint2*)(bp+2);
      b0u.u[0]=lo.x; b0u.u[1]=lo.y; b0u.u[2]=hi.x; b0u.u[3]=hi.y; }
    const uint* bp1 = &Bt[(nt*16 + c15)*34 + 16 + q*4];
    U4 b1u; { uint2 lo = *(const uint2*)bp1; uint2 hi = *(const uint2*)(bp1+2);
      b1u.u[0]=lo.x; b1u.u[1]=lo.y; b1u.u[2]=hi.x; b1u.u[3]=hi.y; }
    bf16x8 b2f = *(const bf16x8*)(VxCT + (size_t)nb*64 + q*8);
    bf16x8 b3f = *(const bf16x8*)(VxCT + (size_t)nb*64 + 32 + q*8);
    acc[nt] = __builtin_amdgcn_mfma_f32_16x16x32_bf16(afr[0], b0u.v, acc[nt], 0,0,0);
    acc[nt] = __builtin_amdgcn_mfma_f32_16x16x32_bf16(afr[1], b1u.v, acc[nt], 0,0,0);
    acc[nt] = __builtin_amdgcn_mfma_f32_16x16x32_bf16(afr[2], b2f, acc[nt], 0,0,0);
    acc[nt] = __builtin_amdgcn_mfma_f32_16x16x32_bf16(afr[3], b3f, acc[nt], 0,0,0);
  }
  float bias = b1[o];
  ushort* xp = x2bf + (size_t)(bb*NW + o)*NPIX;
  #pragma unroll
  for (int nt=0; nt<4; nt++){
    int n = n0 + nt*16 + c15;
    if (n < NSX){
      #pragma unroll
      for (int r=0;r<4;r++){
        int m = m0 + 16*g + q*4 + r;
        if (m < NSY) xp[(size_t)m*NSX + n] = f2bf(acc[nt][r] + bias);
      }
    }
  }
}

// ---------------- pointwise: hbf += (gelu?)(W2 @ gelu(x2) + b2)  (bf16 RMW) ----------------
__global__ __launch_bounds__(256) void k_pw(const ushort* __restrict__ x2bf,
    const float* __restrict__ w2m, const float* __restrict__ b2,
    ushort* __restrict__ hbf, int last, int b0, int nloc){
  int p = blockIdx.x*256 + threadIdx.x;
  if (p >= nloc*NPIX) return;
  int bb = p/NPIX, r = p%NPIX;
  const ushort* xb = x2bf + (size_t)bb*NW*NPIX + r;
  float t[NW];
  #pragma unroll
  for (int c=0;c<NW;c++) t[c] = gelu_f(bf2f(xb[(size_t)c*NPIX]));
  ushort* hb = hbf + (size_t)(b0+bb)*NW*NPIX + r;
  for (int o=0;o<NW;o++){
    float a = b2[o];
    #pragma unroll
    for (int c=0;c<NW;c++) a += t[c]*w2m[o*32+c];
    float g = last ? a : gelu_f(a);
    hb[(size_t)o*NPIX] = f2bf(bf2f(hb[(size_t)o*NPIX]) + g);
  }
}

// ---------------- MFMA fc1 + gelu + fc2 (reads bf16 hbf planar) ----------------
__global__ __launch_bounds__(256) void k_fc12m(const ushort* __restrict__ hbf,
    const ushort* __restrict__ f1Tbf, const float* __restrict__ f1b,
    const float* __restrict__ f2w, const float* __restrict__ f2b,
    float* __restrict__ out){
  int blk = blockIdx.x; int tid = threadIdx.x;
  int g = tid >> 6, lane = tid & 63;
  int c15 = lane & 15, q = lane >> 4;
  int pbase = blk*64 + g*16;
  int pglob = pbase + c15;
  int b = pglob/NPIX, r = pglob%NPIX;
  const ushort* hb = hbf + (size_t)b*NW*NPIX + r;
  U4 au;
  #pragma unroll
  for (int i=0;i<4;i++){
    uint v0 = hb[(size_t)(q*8 + 2*i)*NPIX];
    uint v1 = hb[(size_t)(q*8 + 2*i + 1)*NPIX];
    au.u[i] = v0 | (v1 << 16);
  }
  bf16x8 afr = au.v;
  f32x4 acc[8];
  #pragma unroll
  for (int t=0;t<8;t++) acc[t] = (f32x4){0.f,0.f,0.f,0.f};
  #pragma unroll
  for (int nt=0; nt<8; nt++){
    bf16x8 bfr = *(const bf16x8*)(f1Tbf + (size_t)(nt*16 + c15)*32 + q*8);
    acc[nt] = __builtin_amdgcn_mfma_f32_16x16x32_bf16(afr, bfr, acc[nt], 0,0,0);
  }
  float s[4] = {0.f,0.f,0.f,0.f};
  #pragma unroll
  for (int nt=0; nt<8; nt++){
    int j = nt*16 + c15;
    float bj = f1b[j], wj = f2w[j];
    #pragma unroll
    for (int r2=0;r2<4;r2++) s[r2] += gelu_f(acc[nt][r2] + bj) * wj;
  }
  #pragma unroll
  for (int msk=1; msk<16; msk<<=1){
    #pragma unroll
    for (int r2=0;r2<4;r2++) s[r2] += __shfl_xor(s[r2], msk, 64);
  }
  if (c15 == 0){
    float fb2 = f2b[0];
    float4 v = {s[0]+fb2, s[1]+fb2, s[2]+fb2, s[3]+fb2};
    *(float4*)(out + pbase + q*4) = v;
  }
}

extern "C" void kernel_launch(void* const* d_in, const int* in_sizes, int n_in,
                              void* d_out, int out_size, void* d_ws, size_t ws_size,
                              hipStream_t stream) {
  const float* x     = (const float*)d_in[0];
  const float* sx    = (const float*)d_in[1];
  const float* sy    = (const float*)d_in[2];
  const float* fc0_w = (const float*)d_in[3];
  const float* fc0_b = (const float*)d_in[4];
  const float* fw1   = (const float*)d_in[5];
  const float* fw2   = (const float*)d_in[6];
  const float* w1m   = (const float*)d_in[7];
  const float* b1    = (const float*)d_in[8];
  const float* w2m   = (const float*)d_in[9];
  const float* b2    = (const float*)d_in[10];
  const float* fc1_w = (const float*)d_in[11];
  const float* fc1_b = (const float*)d_in[12];
  const float* fc2_w = (const float*)d_in[13];
  const float* fc2_b = (const float*)d_in[14];
  float* out = (float*)d_out;

  char* wsb = (char*)d_ws;
  size_t off = 0;
  auto alloc = [&](size_t bytes)->char*{
    char* p = wsb + off;
    off = (off + bytes + 255) & ~(size_t)255;
    return p;
  };
  ushort* hbf   = (ushort*)alloc((size_t)NB*NW*NPIX*2);    // 66.4 MB (residual stream)
  ushort* Abfy  = (ushort*)alloc(64*192*2);
  ushort* Abfx  = (ushort*)alloc(64*384*2);
  ushort* VyCT  = (ushort*)alloc(192*64*2);
  ushort* VxCT  = (ushort*)alloc(384*64*2);
  ushort* f1Tbf = (ushort*)alloc(128*32*2);
  float*  gx    = (float*)alloc(NSX*4);
  float*  gy    = (float*)alloc(NSY*4);
  float*  w1f   = (float*)alloc(262144*4);
  float*  w2f   = (float*)alloc(262144*4);
  const size_t fixedB = off;

  // per-batch: x2bf (4,147,200 B) ALIASES [fty | ftx | pad] (ft dead after k_mix)
  const size_t szX2  = (size_t)NW*NPIX*2;
  const size_t szFty = (size_t)NW*32*NSX*4;
  const size_t szFtx = (size_t)NW*32*NSY*4;
  const size_t szOy  = szFty, szOx = szFtx;
  const size_t perB  = szX2 + szOy + szOx;      // 6,359,040 B

  int NC = 16;
  while (NC > 1 && fixedB + (size_t)NC*perB + 4096 > ws_size) NC >>= 1;
  char* pb = wsb + fixedB;
  ushort* x2bf = (ushort*)pb;
  uint*   fty  = (uint*)pb;                               // aliases x2bf head
  uint*   ftx  = (uint*)(pb + (size_t)NC*szFty);          // aliases x2bf tail
  uint*   oy   = (uint*)(pb + (size_t)NC*szX2);
  uint*   ox   = (uint*)((char*)oy + (size_t)NC*szOy);

  k_prep<<<96, 256, 0, stream>>>(sx, sy, fc1_w, Abfy, Abfx, VyCT, VxCT, f1Tbf, gx, gy);
  k_fold<<<1024, 256, 0, stream>>>(fw1, fw2, w1m, w1f, w2f);
  k_fc0<<<4050, 256, 0, stream>>>(x, gx, gy, fc0_w, fc0_b, hbf);

  for (int i=0;i<4;i++){
    for (int b0=0; b0<NB; b0+=NC){
      k_fwd<<<NC*288, 256, 0, stream>>>(hbf, Abfy, Abfx, fty, ftx, b0, NC*192);
      k_mix<<<NC*96, 192, 0, stream>>>(fty, ftx, w1f + (size_t)i*65536,
                                       w2f + (size_t)i*65536, oy, ox, NC*64);
      k_inv<<<NC*576, 256, 0, stream>>>(oy, ox, VyCT, VxCT, b1 + i*32, x2bf);
      k_pw<<<(NC*NPIX + 255)/256, 256, 0, stream>>>(x2bf, w2m + (size_t)i*1024,
                                                    b2 + i*32, hbf, (int)(i==3), b0, NC);
    }
  }

  k_fc12m<<<NPTS/64, 256, 0, stream>>>(hbf, f1Tbf, fc1_b, fc2_w, fc2_b, out);
}

// Round 9
// 1141.346 us; speedup vs baseline: 25.5044x; 1.0658x over previous
//
#include <hip/hip_runtime.h>
#include <math.h>

#define NB 16
#define NSY 180
#define NSX 360
#define NCIN 16
#define NW 32
#define NMODES 32
#define NPIX (NSY*NSX)     // 64800
#define NPTS (NB*NPIX)     // 1036800

typedef unsigned int uint;
typedef unsigned short ushort;
typedef __attribute__((ext_vector_type(8))) short bf16x8;
typedef __attribute__((ext_vector_type(4))) float f32x4;

union U4 { uint u[4]; bf16x8 v; };

// tanh-gelu with fast rcp: v*sigmoid(1.5957691*(v+0.044715 v^3))
__device__ __forceinline__ float gelu_f(float v){
  float u = v*(-1.5957691216f - 0.0713548163f*v*v);
  return v * __builtin_amdgcn_rcpf(1.f + __expf(u));
}
__device__ __forceinline__ ushort f2bf(float x){
  uint u = __float_as_uint(x);
  return (ushort)((u + 0x7FFFu + ((u>>16)&1u)) >> 16);
}
__device__ __forceinline__ uint packbf2(float a, float b){
  return (uint)f2bf(a) | ((uint)f2bf(b) << 16);
}
__device__ __forceinline__ float bf2f(ushort u){
  return __uint_as_float(((uint)u) << 16);
}

// ---------------- prep: bf16 Vandermonde (zero-padded), grid, fc1^T ----------------
__global__ __launch_bounds__(256) void k_prep(const float* __restrict__ sx,
    const float* __restrict__ sy, const float* __restrict__ fc1_w,
    ushort* __restrict__ Abfy, ushort* __restrict__ Abfx,
    ushort* __restrict__ VyCT, ushort* __restrict__ VxCT,
    ushort* __restrict__ f1Tbf, float* __restrict__ gx, float* __restrict__ gy){
  int idx = blockIdx.x*256 + threadIdx.x;
  float sx0 = sx[0], sxL = sx[NSX-1];
  float sy0 = sy[0], syL = sy[NSY-1];
  const float scy = 0.07453559924999298980f;   // 1/sqrt(180)
  const float scx = 0.05270462766947298886f;   // 1/sqrt(360)
  if (idx < NSX) gx[idx] = (sx[idx]-sx0)/sxL;
  if (idx < NSY) gy[idx] = (sy[idx]-sy0)/syL;
  if (idx < 64*192){
    int kri = idx/192, m = idx%192;
    float val = 0.f;
    if (m < NSY){
      int k = kri>>1;
      float p = (sy[m]-sy0)/(syL-sy0);
      float ang = -6.2831853071795864769f*(float)k*p;
      val = ((kri&1)? sinf(ang) : cosf(ang))*scy;
    }
    Abfy[idx] = f2bf(val);
  }
  if (idx < 192*64){
    int m = idx/64, kri = idx%64;
    float val = 0.f;
    if (m < NSY){
      int k = kri>>1;
      float p = (sy[m]-sy0)/(syL-sy0);
      float ang = -6.2831853071795864769f*(float)k*p;
      val = ((kri&1)? sinf(ang) : cosf(ang))*scy;
    }
    VyCT[idx] = f2bf(val);
  }
  if (idx < 64*384){
    int kri = idx/384, n = idx%384;
    float val = 0.f;
    if (n < NSX){
      int k = kri>>1;
      float p = (sx[n]-sx0)/(sxL-sx0);
      float ang = -6.2831853071795864769f*(float)k*p;
      val = ((kri&1)? sinf(ang) : cosf(ang))*scx;
    }
    Abfx[idx] = f2bf(val);
  }
  if (idx < 384*64){
    int n = idx/64, kri = idx%64;
    float val = 0.f;
    if (n < NSX){
      int k = kri>>1;
      float p = (sx[n]-sx0)/(sxL-sx0);
      float ang = -6.2831853071795864769f*(float)k*p;
      val = ((kri&1)? sinf(ang) : cosf(ang))*scx;
    }
    VxCT[idx] = f2bf(val);
  }
  if (idx < 128*32){
    int j = idx >> 5, c = idx & 31;
    f1Tbf[idx] = f2bf(fc1_w[c*128 + j]);
  }
}

// ---------------- fold pointwise w1 into the mode-mix weights (fp32) ----------------
__global__ __launch_bounds__(256) void k_fold(const float* __restrict__ fw1,
    const float* __restrict__ fw2, const float* __restrict__ w1m,
    float* __restrict__ w1f, float* __restrict__ w2f){
  int id = blockIdx.x*256 + threadIdx.x;      // 0..262143
  int half = id >> 17;
  int r = id & 131071;
  int i  = r >> 15;
  int in = (r >> 10) & 31;
  int k  = (r >> 5) & 31;
  int o  = r & 31;
  const float* src = half ? fw2 : fw1;
  const float* wm  = w1m + i*1024 + o*32;
  const float* sp  = src + ((size_t)((i*32+in)*1024 + k))*2;
  float sR = 0.f, sI = 0.f;
  #pragma unroll
  for (int c=0;c<32;c++){
    float w = wm[c];
    sR += w * sp[c*64];
    sI += w * sp[c*64+1];
  }
  float* dst = half ? w2f : w1f;
  size_t oi = ((size_t)((i*32+in)*32 + k)*32 + o)*2;
  dst[oi] = sR; dst[oi+1] = sI;
}

// ---------------- fc0 -> hbf (bf16 residual stream) ----------------
__global__ __launch_bounds__(256) void k_fc0(const float* __restrict__ x,
    const float* __restrict__ gx, const float* __restrict__ gy,
    const float* __restrict__ fw, const float* __restrict__ fb,
    ushort* __restrict__ hbf){
  int p = blockIdx.x*256 + threadIdx.x;
  if (p >= NPTS) return;
  int b = p/NPIX, r = p%NPIX, m = r/NSX, n = r%NSX;
  const float* xp = x + (size_t)p*NCIN;
  float xv[NCIN+2];
  #pragma unroll
  for (int j=0;j<NCIN;j++) xv[j] = xp[j];
  xv[16] = gx[n]; xv[17] = gy[m];
  float acc[NW];
  #pragma unroll
  for (int o=0;o<NW;o++) acc[o] = fb[o];
  #pragma unroll
  for (int j=0;j<NCIN+2;j++){
    float v = xv[j];
    #pragma unroll
    for (int o=0;o<NW;o++) acc[o] += v*fw[j*32+o];
  }
  ushort* hq = hbf + (size_t)b*NW*NPIX + r;
  #pragma unroll
  for (int o=0;o<NW;o++) hq[(size_t)o*NPIX] = f2bf(acc[o]);
}

// ---------------- merged MFMA forward DFTs (y + x in one dispatch) ----------------
__global__ __launch_bounds__(256) void k_fwd(const ushort* __restrict__ hbf,
    const ushort* __restrict__ Abfy, const ushort* __restrict__ Abfx,
    uint* __restrict__ fty, uint* __restrict__ ftx, int b0, int ylim){
  __shared__ uint Bt[64*18];
  int bx = blockIdx.x;
  int tid = threadIdx.x;
  int l = tid & 63, g = tid >> 6;
  int c15 = l & 15, q = l >> 4;
  if (bx < ylim){
    int nt6 = bx % 6; int c = (bx/6) & 31; int bb = bx/192;
    int n0 = nt6*64;
    const ushort* hb = hbf + (size_t)((b0+bb)*NW + c)*NPIX;
    bf16x8 afr[6];
    #pragma unroll
    for (int ks=0; ks<6; ks++)
      afr[ks] = *(const bf16x8*)(Abfy + (size_t)(16*g + c15)*192 + ks*32 + q*8);
    f32x4 acc[4];
    #pragma unroll
    for (int t=0;t<4;t++) acc[t] = (f32x4){0.f,0.f,0.f,0.f};
    int n = n0 + l;
    bool nv = n < NSX;
    for (int ks=0; ks<6; ks++){
      __syncthreads();
      ushort v[8];
      #pragma unroll
      for (int j=0;j<8;j++){
        int m = ks*32 + 8*g + j;
        v[j] = (nv && m < NSY) ? hb[(size_t)m*NSX + n] : (ushort)0;
      }
      #pragma unroll
      for (int i=0;i<4;i++)
        Bt[l*18 + 4*g + i] = (uint)v[2*i] | ((uint)v[2*i+1] << 16);
      __syncthreads();
      #pragma unroll
      for (int nt=0; nt<4; nt++){
        const uint* bp = &Bt[(nt*16 + c15)*18 + q*4];
        U4 bu;
        uint2 lo = *(const uint2*)(bp);
        uint2 hi = *(const uint2*)(bp+2);
        bu.u[0]=lo.x; bu.u[1]=lo.y; bu.u[2]=hi.x; bu.u[3]=hi.y;
        acc[nt] = __builtin_amdgcn_mfma_f32_16x16x32_bf16(afr[ks], bu.v, acc[nt], 0,0,0);
      }
    }
    uint* fb = fty + (size_t)(bb*NW + c)*32*NSX;
    int k0 = 8*g + 2*q;
    #pragma unroll
    for (int nt=0; nt<4; nt++){
      int nn = n0 + nt*16 + c15;
      if (nn < NSX){
        fb[(size_t)k0*NSX + nn]     = packbf2(acc[nt][0], acc[nt][1]);
        fb[(size_t)(k0+1)*NSX + nn] = packbf2(acc[nt][2], acc[nt][3]);
      }
    }
  } else {
    int t = bx - ylim;
    int mt = t % 3; int c = (t/3) & 31; int bb = t/96;
    int m0 = mt*64;
    const ushort* hb = hbf + (size_t)((b0+bb)*NW + c)*NPIX;
    bf16x8 afr[12];
    #pragma unroll
    for (int ks=0; ks<12; ks++)
      afr[ks] = *(const bf16x8*)(Abfx + (size_t)(16*g + c15)*384 + ks*32 + q*8);
    f32x4 acc[4];
    #pragma unroll
    for (int tt=0;tt<4;tt++) acc[tt] = (f32x4){0.f,0.f,0.f,0.f};
    int m = m0 + l;
    bool mv = m < NSY;
    for (int ks=0; ks<12; ks++){
      __syncthreads();
      int nb = ks*32 + 8*g;
      uint4 p = {0u,0u,0u,0u};
      if (mv && nb < NSX) p = *(const uint4*)(hb + (size_t)m*NSX + nb);
      Bt[l*18 + 4*g + 0] = p.x;
      Bt[l*18 + 4*g + 1] = p.y;
      Bt[l*18 + 4*g + 2] = p.z;
      Bt[l*18 + 4*g + 3] = p.w;
      __syncthreads();
      #pragma unroll
      for (int nt=0; nt<4; nt++){
        const uint* bp = &Bt[(nt*16 + c15)*18 + q*4];
        U4 bu;
        uint2 lo = *(const uint2*)(bp);
        uint2 hi = *(const uint2*)(bp+2);
        bu.u[0]=lo.x; bu.u[1]=lo.y; bu.u[2]=hi.x; bu.u[3]=hi.y;
        acc[nt] = __builtin_amdgcn_mfma_f32_16x16x32_bf16(afr[ks], bu.v, acc[nt], 0,0,0);
      }
    }
    uint* fb = ftx + (size_t)(bb*NW + c)*32*NSY;
    int k0 = 8*g + 2*q;
    #pragma unroll
    for (int nt=0; nt<4; nt++){
      int mm = m0 + nt*16 + c15;
      if (mm < NSY){
        fb[(size_t)k0*NSY + mm]     = packbf2(acc[nt][0], acc[nt][1]);
        fb[(size_t)(k0+1)*NSY + mm] = packbf2(acc[nt][2], acc[nt][3]);
      }
    }
  }
}

// ---------------- unified per-mode complex channel mix (y + x in one dispatch) ----------------
__global__ __launch_bounds__(192) void k_mix(const uint* __restrict__ fty,
    const uint* __restrict__ ftx, const float* __restrict__ w1f,
    const float* __restrict__ w2f, uint* __restrict__ oy, uint* __restrict__ ox,
    int ylim){
  int bx = blockIdx.x;
  const uint* ft; const float* wf; uint* oo; int Nlen, k, bb, n;
  if (bx < ylim){
    int t = bx; int nt = t & 1; k = (t>>1) & 31; bb = t >> 6;
    n = nt*192 + threadIdx.x; ft = fty; wf = w1f; oo = oy; Nlen = NSX;
  } else {
    int t = bx - ylim; k = t & 31; bb = t >> 5;
    n = threadIdx.x; ft = ftx; wf = w2f; oo = ox; Nlen = NSY;
  }
  bool valid = n < Nlen;
  int nn = valid ? n : (Nlen-1);
  const uint* fb = ft + ((size_t)(bb*NW)*32 + k)*Nlen + nn;
  const float* wb = wf + (size_t)k*64;
  float aR[32], aI[32];
  #pragma unroll
  for (int o=0;o<32;o++){ aR[o]=0.f; aI[o]=0.f; }
  for (int in=0; in<32; in++){
    uint f = fb[(size_t)in*32*Nlen];
    float fR = bf2f((ushort)(f & 0xffffu));
    float fI = bf2f((ushort)(f >> 16));
    const float* wrow = wb + in*2048;
    #pragma unroll
    for (int o=0;o<32;o++){
      float wR = wrow[o*2], wI = wrow[o*2+1];
      aR[o] += fR*wR - fI*wI;
      aI[o] += fR*wI + fI*wR;
    }
  }
  if (valid){
    uint* ob = oo + ((size_t)(bb*NW)*32 + k)*Nlen + n;
    #pragma unroll
    for (int o=0;o<32;o++){
      ob[(size_t)o*32*Nlen] = packbf2(aR[o], aI[o]);
    }
  }
}

// ---------------- MFMA inverse (y+x combined), full-M blocks, XCD-swizzled ----------------
// One block per (bb, o, n-tile of 64). Stages ALL m of ox once (At) + oy slice (Bt).
// Wave g computes m-tiles 3g..3g+2 x 4 n-tiles, K=128 in 4 steps.
__global__ __launch_bounds__(256) void k_inv(const uint* __restrict__ oyb,
    const uint* __restrict__ oxb, const ushort* __restrict__ VyCT,
    const ushort* __restrict__ VxCT, const float* __restrict__ b1,
    ushort* __restrict__ x2bf){
  __shared__ uint At[192*34];   // [m][k] 26.1 KB
  __shared__ uint Bt[64*34];    // [n][k]  8.7 KB
  int bx = blockIdx.x;
  // swizzle: 6 blocks of one (bb,o) share an XCD (assumes round-robin bx%8->XCD)
  int c8 = bx & 7; int rr = bx >> 3; int slot = rr/6; int nt6 = rr - slot*6;
  int gid = slot*8 + c8;
  int bb = gid >> 5; int o = gid & 31;
  int n0 = nt6*64;
  int tid = threadIdx.x;
  int l = tid & 63, g = tid >> 6;
  int c15 = l & 15, q = l >> 4;
  const uint* oxp = oxb + (size_t)(bb*NW + o)*32*NSY;
  const uint* oyp = oyb + (size_t)(bb*NW + o)*32*NSX;
  #pragma unroll
  for (int i=0;i<24;i++){
    int idx = tid + i*256;          // < 6144
    int k = idx/192, m = idx - k*192;
    At[m*34 + k] = (m < NSY) ? oxp[(size_t)k*NSY + m] : 0u;
  }
  #pragma unroll
  for (int i=0;i<8;i++){
    int idx = tid + i*256;          // < 2048
    int k = idx >> 6, n = idx & 63;
    int ng = n0 + n;
    Bt[n*34 + k] = (ng < NSX) ? oyp[(size_t)k*NSX + ng] : 0u;
  }
  __syncthreads();
  f32x4 acc[3][4];
  #pragma unroll
  for (int mt=0;mt<3;mt++)
    #pragma unroll
    for (int nt=0;nt<4;nt++) acc[mt][nt] = (f32x4){0.f,0.f,0.f,0.f};
  #pragma unroll
  for (int s=0;s<4;s++){
    bf16x8 bfr[4];
    #pragma unroll
    for (int nt=0;nt<4;nt++){
      if (s < 2){
        const uint* bp = &Bt[(nt*16 + c15)*34 + s*16 + q*4];
        U4 bu; uint2 lo = *(const uint2*)bp; uint2 hi = *(const uint2*)(bp+2);
        bu.u[0]=lo.x; bu.u[1]=lo.y; bu.u[2]=hi.x; bu.u[3]=hi.y;
        bfr[nt] = bu.v;
      } else {
        bfr[nt] = *(const bf16x8*)(VxCT + (size_t)(n0 + nt*16 + c15)*64 + (s-2)*32 + q*8);
      }
    }
    #pragma unroll
    for (int mt=0;mt<3;mt++){
      int mrow = g*48 + mt*16 + c15;
      bf16x8 afr;
      if (s < 2){
        afr = *(const bf16x8*)(VyCT + (size_t)mrow*64 + s*32 + q*8);
      } else {
        const uint* ap = &At[mrow*34 + (s-2)*16 + q*4];
        U4 au; uint2 lo = *(const uint2*)ap; uint2 hi = *(const uint2*)(ap+2);
        au.u[0]=lo.x; au.u[1]=lo.y; au.u[2]=hi.x; au.u[3]=hi.y;
        afr = au.v;
      }
      #pragma unroll
      for (int nt=0;nt<4;nt++)
        acc[mt][nt] = __builtin_amdgcn_mfma_f32_16x16x32_bf16(afr, bfr[nt], acc[mt][nt], 0,0,0);
    }
  }
  float bias = b1[o];
  ushort* xp = x2bf + (size_t)(bb*NW + o)*NPIX;
  #pragma unroll
  for (int mt=0;mt<3;mt++){
    #pragma unroll
    for (int nt=0;nt<4;nt++){
      int n = n0 + nt*16 + c15;
      if (n < NSX){
        #pragma unroll
        for (int r2=0;r2<4;r2++){
          int m = g*48 + mt*16 + q*4 + r2;
          if (m < NSY) xp[(size_t)m*NSX + n] = f2bf(acc[mt][nt][r2] + bias);
        }
      }
    }
  }
}

// ---------------- pointwise (2 pixels/thread): hbf += (gelu?)(W2 @ gelu(x2) + b2) ----------------
__global__ __launch_bounds__(256) void k_pw(const uint* __restrict__ x2u,
    const float* __restrict__ w2m, const float* __restrict__ b2,
    uint* __restrict__ hbfu, int last, int b0, int nloc){
  const int HP = NPIX/2;   // 32400
  int p2 = blockIdx.x*256 + threadIdx.x;
  if (p2 >= nloc*HP) return;
  int bb = p2/HP, r = p2%HP;
  const uint* xb = x2u + (size_t)bb*NW*HP + r;
  float t0[NW], t1[NW];
  #pragma unroll
  for (int c=0;c<NW;c++){
    uint f = xb[(size_t)c*HP];
    t0[c] = gelu_f(bf2f((ushort)(f & 0xffffu)));
    t1[c] = gelu_f(bf2f((ushort)(f >> 16)));
  }
  uint* hb = hbfu + (size_t)(b0+bb)*NW*HP + r;
  for (int o=0;o<NW;o++){
    float a0 = b2[o], a1 = a0;
    const float* wr = w2m + o*32;
    #pragma unroll
    for (int c=0;c<NW;c++){
      a0 += t0[c]*wr[c];
      a1 += t1[c]*wr[c];
    }
    float g0 = last ? a0 : gelu_f(a0);
    float g1 = last ? a1 : gelu_f(a1);
    uint hv = hb[(size_t)o*HP];
    hb[(size_t)o*HP] = packbf2(bf2f((ushort)(hv & 0xffffu)) + g0,
                               bf2f((ushort)(hv >> 16)) + g1);
  }
}

// ---------------- MFMA fc1 + gelu + fc2 (reads bf16 hbf planar) ----------------
__global__ __launch_bounds__(256) void k_fc12m(const ushort* __restrict__ hbf,
    const ushort* __restrict__ f1Tbf, const float* __restrict__ f1b,
    const float* __restrict__ f2w, const float* __restrict__ f2b,
    float* __restrict__ out){
  int blk = blockIdx.x; int tid = threadIdx.x;
  int g = tid >> 6, lane = tid & 63;
  int c15 = lane & 15, q = lane >> 4;
  int pbase = blk*64 + g*16;
  int pglob = pbase + c15;
  int b = pglob/NPIX, r = pglob%NPIX;
  const ushort* hb = hbf + (size_t)b*NW*NPIX + r;
  U4 au;
  #pragma unroll
  for (int i=0;i<4;i++){
    uint v0 = hb[(size_t)(q*8 + 2*i)*NPIX];
    uint v1 = hb[(size_t)(q*8 + 2*i + 1)*NPIX];
    au.u[i] = v0 | (v1 << 16);
  }
  bf16x8 afr = au.v;
  f32x4 acc[8];
  #pragma unroll
  for (int t=0;t<8;t++) acc[t] = (f32x4){0.f,0.f,0.f,0.f};
  #pragma unroll
  for (int nt=0; nt<8; nt++){
    bf16x8 bfr = *(const bf16x8*)(f1Tbf + (size_t)(nt*16 + c15)*32 + q*8);
    acc[nt] = __builtin_amdgcn_mfma_f32_16x16x32_bf16(afr, bfr, acc[nt], 0,0,0);
  }
  float s[4] = {0.f,0.f,0.f,0.f};
  #pragma unroll
  for (int nt=0; nt<8; nt++){
    int j = nt*16 + c15;
    float bj = f1b[j], wj = f2w[j];
    #pragma unroll
    for (int r2=0;r2<4;r2++) s[r2] += gelu_f(acc[nt][r2] + bj) * wj;
  }
  #pragma unroll
  for (int msk=1; msk<16; msk<<=1){
    #pragma unroll
    for (int r2=0;r2<4;r2++) s[r2] += __shfl_xor(s[r2], msk, 64);
  }
  if (c15 == 0){
    float fb2 = f2b[0];
    float4 v = {s[0]+fb2, s[1]+fb2, s[2]+fb2, s[3]+fb2};
    *(float4*)(out + pbase + q*4) = v;
  }
}

extern "C" void kernel_launch(void* const* d_in, const int* in_sizes, int n_in,
                              void* d_out, int out_size, void* d_ws, size_t ws_size,
                              hipStream_t stream) {
  const float* x     = (const float*)d_in[0];
  const float* sx    = (const float*)d_in[1];
  const float* sy    = (const float*)d_in[2];
  const float* fc0_w = (const float*)d_in[3];
  const float* fc0_b = (const float*)d_in[4];
  const float* fw1   = (const float*)d_in[5];
  const float* fw2   = (const float*)d_in[6];
  const float* w1m   = (const float*)d_in[7];
  const float* b1    = (const float*)d_in[8];
  const float* w2m   = (const float*)d_in[9];
  const float* b2    = (const float*)d_in[10];
  const float* fc1_w = (const float*)d_in[11];
  const float* fc1_b = (const float*)d_in[12];
  const float* fc2_w = (const float*)d_in[13];
  const float* fc2_b = (const float*)d_in[14];
  float* out = (float*)d_out;

  char* wsb = (char*)d_ws;
  size_t off = 0;
  auto alloc = [&](size_t bytes)->char*{
    char* p = wsb + off;
    off = (off + bytes + 255) & ~(size_t)255;
    return p;
  };
  ushort* hbf   = (ushort*)alloc((size_t)NB*NW*NPIX*2);    // 66.4 MB (residual stream)
  ushort* Abfy  = (ushort*)alloc(64*192*2);
  ushort* Abfx  = (ushort*)alloc(64*384*2);
  ushort* VyCT  = (ushort*)alloc(192*64*2);
  ushort* VxCT  = (ushort*)alloc(384*64*2);
  ushort* f1Tbf = (ushort*)alloc(128*32*2);
  float*  gx    = (float*)alloc(NSX*4);
  float*  gy    = (float*)alloc(NSY*4);
  float*  w1f   = (float*)alloc(262144*4);
  float*  w2f   = (float*)alloc(262144*4);
  const size_t fixedB = off;

  // per-batch: x2bf (4,147,200 B) ALIASES [fty | ftx | pad] (ft dead after k_mix)
  const size_t szX2  = (size_t)NW*NPIX*2;
  const size_t szFty = (size_t)NW*32*NSX*4;
  const size_t szFtx = (size_t)NW*32*NSY*4;
  const size_t szOy  = szFty, szOx = szFtx;
  const size_t perB  = szX2 + szOy + szOx;      // 6,359,040 B

  int NC = 16;
  while (NC > 1 && fixedB + (size_t)NC*perB + 4096 > ws_size) NC >>= 1;
  char* pb = wsb + fixedB;
  ushort* x2bf = (ushort*)pb;
  uint*   fty  = (uint*)pb;                               // aliases x2bf head
  uint*   ftx  = (uint*)(pb + (size_t)NC*szFty);          // aliases x2bf tail
  uint*   oy   = (uint*)(pb + (size_t)NC*szX2);
  uint*   ox   = (uint*)((char*)oy + (size_t)NC*szOy);

  k_prep<<<96, 256, 0, stream>>>(sx, sy, fc1_w, Abfy, Abfx, VyCT, VxCT, f1Tbf, gx, gy);
  k_fold<<<1024, 256, 0, stream>>>(fw1, fw2, w1m, w1f, w2f);
  k_fc0<<<4050, 256, 0, stream>>>(x, gx, gy, fc0_w, fc0_b, hbf);

  for (int i=0;i<4;i++){
    for (int b0=0; b0<NB; b0+=NC){
      k_fwd<<<NC*288, 256, 0, stream>>>(hbf, Abfy, Abfx, fty, ftx, b0, NC*192);
      k_mix<<<NC*96, 192, 0, stream>>>(fty, ftx, w1f + (size_t)i*65536,
                                       w2f + (size_t)i*65536, oy, ox, NC*64);
      k_inv<<<NC*192, 256, 0, stream>>>(oy, ox, VyCT, VxCT, b1 + i*32, x2bf);
      k_pw<<<(NC*(NPIX/2) + 255)/256, 256, 0, stream>>>((const uint*)x2bf,
                                                    w2m + (size_t)i*1024,
                                                    b2 + i*32, (uint*)hbf,
                                                    (int)(i==3), b0, NC);
    }
  }

  k_fc12m<<<NPTS/64, 256, 0, stream>>>(hbf, f1Tbf, fc1_b, fc2_w, fc2_b, out);
}